// Round 1
// baseline (9373.553 us; speedup 1.0000x reference)
//
#include <hip/hip_runtime.h>
#include <math.h>

static constexpr int Nn  = 20000;
static constexpr int Ne  = 320000;
static constexpr int DIN = 128;
static constexpr int DOUTc = 10;
static constexpr int Hc  = 1024;
static constexpr int HMc = 256;
static constexpr float EPSc = 1e-5f;

// ---------------- degree / dinv ----------------
__global__ __launch_bounds__(256) void deg_init_k(float* __restrict__ deg) {
    int i = blockIdx.x * 256 + threadIdx.x;
    if (i < Nn) deg[i] = 1.0f;  // self-loop weight
}

__global__ __launch_bounds__(256) void deg_edge_k(const float* __restrict__ w,
                                                  const int* __restrict__ dstv,
                                                  float* __restrict__ deg) {
    int e = blockIdx.x * 256 + threadIdx.x;
    if (e < Ne) atomicAdd(&deg[dstv[e]], w[e]);
}

__global__ __launch_bounds__(256) void dinv_k(float* __restrict__ deg) {
    int i = blockIdx.x * 256 + threadIdx.x;
    if (i < Nn) deg[i] = rsqrtf(deg[i]);  // deg >= 1 always
}

// ---------------- fp32 tiled GEMM: C[M x NC] = A[M x KD] @ B[KD x NC] ----------------
template<int NC, int KD, bool BIAS, bool RELU>
__global__ __launch_bounds__(256)
void gemm_k(const float* __restrict__ A, const float* __restrict__ B,
            const float* __restrict__ bias, float* __restrict__ C, int M)
{
    __shared__ float As[16][64];   // As[k][m]
    __shared__ float Bs[16][64];   // Bs[k][n]
    const int tid = threadIdx.x;
    const int bm = blockIdx.y * 64;
    const int bn = blockIdx.x * 64;
    const int tx = tid & 15;        // n micro
    const int ty = tid >> 4;        // m micro
    const int ar = tid >> 2;        // A tile row (0..63)
    const int ac = (tid & 3) << 2;  // A tile col (k) 0,4,8,12
    const int br = tid >> 4;        // B tile row (k) 0..15
    const int bc = (tid & 15) << 2; // B tile col
    float acc[4][4] = {};

    for (int k0 = 0; k0 < KD; k0 += 16) {
        int arow = bm + ar;
        float4 av = make_float4(0.f, 0.f, 0.f, 0.f);
        if (arow < M) av = *(const float4*)(A + (size_t)arow * KD + k0 + ac);
        As[ac + 0][ar] = av.x;
        As[ac + 1][ar] = av.y;
        As[ac + 2][ar] = av.z;
        As[ac + 3][ar] = av.w;
        *(float4*)&Bs[br][bc] = *(const float4*)(B + (size_t)(k0 + br) * NC + bn + bc);
        __syncthreads();
        #pragma unroll
        for (int k = 0; k < 16; ++k) {
            float4 a = *(const float4*)&As[k][ty << 2];
            float4 b = *(const float4*)&Bs[k][tx << 2];
            acc[0][0] = fmaf(a.x, b.x, acc[0][0]);
            acc[0][1] = fmaf(a.x, b.y, acc[0][1]);
            acc[0][2] = fmaf(a.x, b.z, acc[0][2]);
            acc[0][3] = fmaf(a.x, b.w, acc[0][3]);
            acc[1][0] = fmaf(a.y, b.x, acc[1][0]);
            acc[1][1] = fmaf(a.y, b.y, acc[1][1]);
            acc[1][2] = fmaf(a.y, b.z, acc[1][2]);
            acc[1][3] = fmaf(a.y, b.w, acc[1][3]);
            acc[2][0] = fmaf(a.z, b.x, acc[2][0]);
            acc[2][1] = fmaf(a.z, b.y, acc[2][1]);
            acc[2][2] = fmaf(a.z, b.z, acc[2][2]);
            acc[2][3] = fmaf(a.z, b.w, acc[2][3]);
            acc[3][0] = fmaf(a.w, b.x, acc[3][0]);
            acc[3][1] = fmaf(a.w, b.y, acc[3][1]);
            acc[3][2] = fmaf(a.w, b.z, acc[3][2]);
            acc[3][3] = fmaf(a.w, b.w, acc[3][3]);
        }
        __syncthreads();
    }

    #pragma unroll
    for (int i = 0; i < 4; ++i) {
        int row = bm + (ty << 2) + i;
        if (row >= M) continue;
        #pragma unroll
        for (int j = 0; j < 4; ++j) {
            int col = bn + (tx << 2) + j;
            float v = acc[i][j];
            if (BIAS) v += bias[col];
            if (RELU) v = fmaxf(v, 0.f);
            C[(size_t)row * NC + col] = v;
        }
    }
}

// ---------------- aggregation ----------------
// self-loop term: agg[i] = dinv[i]^2 * h[i]
__global__ __launch_bounds__(256)
void agg_self_k(const float4* __restrict__ h, const float* __restrict__ dinv,
                float4* __restrict__ agg)
{
    int idx = blockIdx.x * 256 + threadIdx.x;      // < Nn*Hc/4 (exact grid)
    int node = idx >> 8;                           // Hc/4 = 256
    float c = dinv[node];
    c = c * c;
    float4 v = h[idx];
    agg[idx] = make_float4(c * v.x, c * v.y, c * v.z, c * v.w);
}

// edge term: agg[dst] += dinv[src]*w*dinv[dst] * h[src]
__global__ __launch_bounds__(256)
void agg_edge_k(const float* __restrict__ h, const int* __restrict__ srcv,
                const int* __restrict__ dstv, const float* __restrict__ w,
                const float* __restrict__ dinv, float* __restrict__ agg)
{
    int e = blockIdx.x;
    int s = srcv[e];
    int d = dstv[e];
    float coeff = dinv[s] * w[e] * dinv[d];
    const float4* hs = (const float4*)(h + (size_t)s * Hc);
    float* ad = agg + (size_t)d * Hc;
    int f = threadIdx.x;                           // Hc/4 == 256 == blockDim
    float4 v = hs[f];
    atomicAdd(ad + 4 * f + 0, coeff * v.x);
    atomicAdd(ad + 4 * f + 1, coeff * v.y);
    atomicAdd(ad + 4 * f + 2, coeff * v.z);
    atomicAdd(ad + 4 * f + 3, coeff * v.w);
}

// ---------------- batchnorm ----------------
__global__ __launch_bounds__(256) void zero_stats_k(float* __restrict__ s) {
    int i = blockIdx.x * 256 + threadIdx.x;        // grid 8 -> 2048 = 2*Hc
    s[i] = 0.f;
}

__global__ __launch_bounds__(256)
void bn_stats_k(const float* __restrict__ x, float* __restrict__ s1, float* __restrict__ s2)
{
    int c = blockIdx.x * 256 + threadIdx.x;        // < Hc
    int r0 = blockIdx.y * 250;                     // 80 chunks * 250 = 20000
    float s = 0.f, q = 0.f;
    const float* p = x + (size_t)r0 * Hc + c;
    for (int r = 0; r < 250; ++r) {
        float v = p[(size_t)r * Hc];
        s += v;
        q = fmaf(v, v, q);
    }
    atomicAdd(&s1[c], s);
    atomicAdd(&s2[c], q);
}

__global__ __launch_bounds__(256)
void bn_finalize_k(float* __restrict__ s1, float* __restrict__ s2,
                   const float* __restrict__ g, const float* __restrict__ beta)
{
    int c = blockIdx.x * 256 + threadIdx.x;
    if (c >= Hc) return;
    float mean = s1[c] * (1.0f / Nn);
    float var  = s2[c] * (1.0f / Nn) - mean * mean;
    float rstd = rsqrtf(var + EPSc);
    float sc = g[c] * rstd;
    s1[c] = sc;                       // scale
    s2[c] = beta[c] - mean * sc;      // shift
}

__global__ __launch_bounds__(256)
void bn_apply_k(float4* __restrict__ x, const float* __restrict__ scale,
                const float* __restrict__ shift)
{
    int idx = blockIdx.x * 256 + threadIdx.x;      // < Nn*Hc/4 (exact grid)
    int c4 = (idx & (Hc / 4 - 1)) << 2;
    float4 sc = *(const float4*)(scale + c4);
    float4 sh = *(const float4*)(shift + c4);
    float4 v = x[idx];
    v.x = fmaxf(fmaf(v.x, sc.x, sh.x), 0.f);
    v.y = fmaxf(fmaf(v.y, sc.y, sh.y), 0.f);
    v.z = fmaxf(fmaf(v.z, sc.z, sh.z), 0.f);
    v.w = fmaxf(fmaf(v.w, sc.w, sh.w), 0.f);
    x[idx] = v;
}

// ---------------- head: out = log_softmax(z @ Wl2 + bl2) ----------------
__global__ __launch_bounds__(256)
void head_k(const float* __restrict__ z, const float* __restrict__ Wl2,
            const float* __restrict__ bl2, float* __restrict__ out)
{
    int wave = threadIdx.x >> 6;
    int lane = threadIdx.x & 63;
    int node = blockIdx.x * 4 + wave;              // grid = Nn/4 exact
    const float4 zv = *(const float4*)(z + (size_t)node * HMc + lane * 4);
    float p[DOUTc];
    #pragma unroll
    for (int j = 0; j < DOUTc; ++j) p[j] = 0.f;
    const float zz[4] = {zv.x, zv.y, zv.z, zv.w};
    #pragma unroll
    for (int i = 0; i < 4; ++i) {
        int k = lane * 4 + i;
        const float* wrow = Wl2 + (size_t)k * DOUTc;
        #pragma unroll
        for (int j = 0; j < DOUTc; ++j) p[j] = fmaf(zz[i], wrow[j], p[j]);
    }
    #pragma unroll
    for (int j = 0; j < DOUTc; ++j) {
        #pragma unroll
        for (int off = 32; off > 0; off >>= 1) p[j] += __shfl_down(p[j], off, 64);
    }
    if (lane == 0) {
        float v[DOUTc];
        float m = -1e30f;
        #pragma unroll
        for (int j = 0; j < DOUTc; ++j) { v[j] = p[j] + bl2[j]; m = fmaxf(m, v[j]); }
        float s = 0.f;
        #pragma unroll
        for (int j = 0; j < DOUTc; ++j) s += expf(v[j] - m);
        float ls = logf(s) + m;
        #pragma unroll
        for (int j = 0; j < DOUTc; ++j) out[(size_t)node * DOUTc + j] = v[j] - ls;
    }
}

// ---------------- launch ----------------
extern "C" void kernel_launch(void* const* d_in, const int* in_sizes, int n_in,
                              void* d_out, int out_size, void* d_ws, size_t ws_size,
                              hipStream_t stream)
{
    (void)in_sizes; (void)n_in; (void)out_size; (void)ws_size;
    const float* x    = (const float*)d_in[0];
    const int*   ei   = (const int*)d_in[1];
    const float* ew   = (const float*)d_in[2];
    const float* W1   = (const float*)d_in[3];
    // b1 = d_in[4]: cancels under batchnorm mean-subtraction
    const float* gam1 = (const float*)d_in[5];
    const float* bet1 = (const float*)d_in[6];
    const float* W2   = (const float*)d_in[7];
    // b2 = d_in[8]: cancels
    const float* gam2 = (const float*)d_in[9];
    const float* bet2 = (const float*)d_in[10];
    const float* Wl1  = (const float*)d_in[11];
    const float* bl1  = (const float*)d_in[12];
    const float* Wl2  = (const float*)d_in[13];
    const float* bl2  = (const float*)d_in[14];
    float* out = (float*)d_out;

    float* bufA = (float*)d_ws;                    // Nn*Hc
    float* bufB = bufA + (size_t)Nn * Hc;          // Nn*Hc
    float* dinv = bufB + (size_t)Nn * Hc;          // Nn
    float* s1   = dinv + Nn;                       // Hc
    float* s2   = s1 + Hc;                         // Hc

    const int* srcv = ei;
    const int* dstv = ei + Ne;

    const int EW4 = Nn * Hc / 4 / 256;             // 20000 blocks for elementwise f4

    // degree -> dinv
    deg_init_k<<<(Nn + 255) / 256, 256, 0, stream>>>(dinv);
    deg_edge_k<<<(Ne + 255) / 256, 256, 0, stream>>>(ew, dstv, dinv);
    dinv_k<<<(Nn + 255) / 256, 256, 0, stream>>>(dinv);

    dim3 ggrid(Hc / 64, (Nn + 63) / 64);

    // layer 1
    gemm_k<Hc, DIN, false, false><<<ggrid, 256, 0, stream>>>(x, W1, nullptr, bufA, Nn);
    agg_self_k<<<EW4, 256, 0, stream>>>((const float4*)bufA, dinv, (float4*)bufB);
    agg_edge_k<<<Ne, 256, 0, stream>>>(bufA, srcv, dstv, ew, dinv, bufB);
    zero_stats_k<<<8, 256, 0, stream>>>(s1);
    bn_stats_k<<<dim3(Hc / 256, 80), 256, 0, stream>>>(bufB, s1, s2);
    bn_finalize_k<<<Hc / 256, 256, 0, stream>>>(s1, s2, gam1, bet1);
    bn_apply_k<<<EW4, 256, 0, stream>>>((float4*)bufB, s1, s2);

    // layer 2
    gemm_k<Hc, Hc, false, false><<<ggrid, 256, 0, stream>>>(bufB, W2, nullptr, bufA, Nn);
    agg_self_k<<<EW4, 256, 0, stream>>>((const float4*)bufA, dinv, (float4*)bufB);
    agg_edge_k<<<Ne, 256, 0, stream>>>(bufA, srcv, dstv, ew, dinv, bufB);
    zero_stats_k<<<8, 256, 0, stream>>>(s1);
    bn_stats_k<<<dim3(Hc / 256, 80), 256, 0, stream>>>(bufB, s1, s2);
    bn_finalize_k<<<Hc / 256, 256, 0, stream>>>(s1, s2, gam2, bet2);
    bn_apply_k<<<EW4, 256, 0, stream>>>((float4*)bufB, s1, s2);

    // MLP head: z = relu(h @ Wl1 + bl1) into bufA (reuse), then fused GEMM4+log_softmax
    gemm_k<HMc, Hc, true, true><<<dim3(HMc / 64, (Nn + 63) / 64), 256, 0, stream>>>(bufB, Wl1, bl1, bufA, Nn);
    head_k<<<Nn / 4, 256, 0, stream>>>(bufA, Wl2, bl2, out);
}

// Round 2
// 1468.894 us; speedup vs baseline: 6.3814x; 6.3814x over previous
//
#include <hip/hip_runtime.h>
#include <math.h>

static constexpr int Nn  = 20000;
static constexpr int Ne  = 320000;
static constexpr int DIN = 128;
static constexpr int DOUTc = 10;
static constexpr int Hc  = 1024;
static constexpr int HMc = 256;
static constexpr float EPSc = 1e-5f;

// ---------------- degree / count init ----------------
__global__ __launch_bounds__(256) void deg_init_k(float* __restrict__ deg, int* __restrict__ cnt) {
    int i = blockIdx.x * 256 + threadIdx.x;
    if (i < Nn) { deg[i] = 1.0f; cnt[i] = 0; }     // self-loop weight 1
}

__global__ __launch_bounds__(256)
void deg_edge_k(const float* __restrict__ w, const int* __restrict__ dstv,
                float* __restrict__ deg, int* __restrict__ cnt) {
    int e = blockIdx.x * 256 + threadIdx.x;
    if (e < Ne) {
        int d = dstv[e];
        atomicAdd(&deg[d], w[e]);
        atomicAdd(&cnt[d], 1);
    }
}

__global__ __launch_bounds__(256) void dinv_k(float* __restrict__ deg) {
    int i = blockIdx.x * 256 + threadIdx.x;
    if (i < Nn) deg[i] = rsqrtf(deg[i]);  // deg >= 1 always
}

// ---------------- single-block exclusive scan over cnt -> row_ptr, cursor ----------------
__global__ __launch_bounds__(1024)
void scan_k(const int* __restrict__ cnt, int* __restrict__ row_ptr, int* __restrict__ cursor)
{
    __shared__ int sm[1024];
    __shared__ int carry_s;
    int tid = threadIdx.x;
    if (tid == 0) carry_s = 0;
    __syncthreads();
    for (int base = 0; base < Nn; base += 1024) {
        int i = base + tid;
        int v = (i < Nn) ? cnt[i] : 0;
        sm[tid] = v;
        __syncthreads();
        #pragma unroll
        for (int off = 1; off < 1024; off <<= 1) {
            int t = (tid >= off) ? sm[tid - off] : 0;
            __syncthreads();
            sm[tid] += t;
            __syncthreads();
        }
        int incl = sm[tid];
        int carry = carry_s;
        if (i < Nn) {
            int excl = carry + incl - v;
            row_ptr[i] = excl;
            cursor[i]  = excl;
        }
        __syncthreads();
        if (tid == 1023) carry_s = carry + incl;
        __syncthreads();
    }
    if (tid == 0) row_ptr[Nn] = Ne;
}

// ---------------- CSR fill (coeff precomputed) ----------------
__global__ __launch_bounds__(256)
void csr_fill_k(const int* __restrict__ srcv, const int* __restrict__ dstv,
                const float* __restrict__ w, const float* __restrict__ dinv,
                int* __restrict__ cursor, int* __restrict__ csr_src,
                float* __restrict__ csr_coeff)
{
    int e = blockIdx.x * 256 + threadIdx.x;
    if (e >= Ne) return;
    int s = srcv[e], d = dstv[e];
    int pos = atomicAdd(&cursor[d], 1);
    csr_src[pos]   = s;
    csr_coeff[pos] = dinv[s] * w[e] * dinv[d];
}

// ---------------- gather SpMM: out[d] = dinv[d]^2*h[d] + sum_e coeff*h[src] ----------------
__global__ __launch_bounds__(256)
void spmm_k(const float4* __restrict__ h4, const int* __restrict__ row_ptr,
            const int* __restrict__ csr_src, const float* __restrict__ csr_coeff,
            const float* __restrict__ dinv, float4* __restrict__ out4)
{
    int d = blockIdx.x;                 // grid = Nn
    int f = threadIdx.x;                // 0..255, owns float4 (Hc/4 == 256)
    float c = dinv[d]; c = c * c;
    float4 acc = h4[(size_t)d * 256 + f];
    acc.x *= c; acc.y *= c; acc.z *= c; acc.w *= c;
    int beg = row_ptr[d], end = row_ptr[d + 1];
    for (int j = beg; j < end; ++j) {
        int   s  = csr_src[j];
        float cf = csr_coeff[j];
        float4 v = h4[(size_t)s * 256 + f];
        acc.x = fmaf(cf, v.x, acc.x);
        acc.y = fmaf(cf, v.y, acc.y);
        acc.z = fmaf(cf, v.z, acc.z);
        acc.w = fmaf(cf, v.w, acc.w);
    }
    out4[(size_t)d * 256 + f] = acc;
}

// ---------------- fp32 tiled GEMM: C[M x NC] = A[M x KD] @ B[KD x NC] ----------------
template<int NC, int KD, bool BIAS, bool RELU>
__global__ __launch_bounds__(256)
void gemm_k(const float* __restrict__ A, const float* __restrict__ B,
            const float* __restrict__ bias, float* __restrict__ C, int M)
{
    __shared__ float As[16][64];   // As[k][m]
    __shared__ float Bs[16][64];   // Bs[k][n]
    const int tid = threadIdx.x;
    const int bm = blockIdx.y * 64;
    const int bn = blockIdx.x * 64;
    const int tx = tid & 15;        // n micro
    const int ty = tid >> 4;        // m micro
    const int ar = tid >> 2;        // A tile row (0..63)
    const int ac = (tid & 3) << 2;  // A tile col (k) 0,4,8,12
    const int br = tid >> 4;        // B tile row (k) 0..15
    const int bc = (tid & 15) << 2; // B tile col
    float acc[4][4] = {};

    for (int k0 = 0; k0 < KD; k0 += 16) {
        int arow = bm + ar;
        float4 av = make_float4(0.f, 0.f, 0.f, 0.f);
        if (arow < M) av = *(const float4*)(A + (size_t)arow * KD + k0 + ac);
        As[ac + 0][ar] = av.x;
        As[ac + 1][ar] = av.y;
        As[ac + 2][ar] = av.z;
        As[ac + 3][ar] = av.w;
        *(float4*)&Bs[br][bc] = *(const float4*)(B + (size_t)(k0 + br) * NC + bn + bc);
        __syncthreads();
        #pragma unroll
        for (int k = 0; k < 16; ++k) {
            float4 a = *(const float4*)&As[k][ty << 2];
            float4 b = *(const float4*)&Bs[k][tx << 2];
            acc[0][0] = fmaf(a.x, b.x, acc[0][0]);
            acc[0][1] = fmaf(a.x, b.y, acc[0][1]);
            acc[0][2] = fmaf(a.x, b.z, acc[0][2]);
            acc[0][3] = fmaf(a.x, b.w, acc[0][3]);
            acc[1][0] = fmaf(a.y, b.x, acc[1][0]);
            acc[1][1] = fmaf(a.y, b.y, acc[1][1]);
            acc[1][2] = fmaf(a.y, b.z, acc[1][2]);
            acc[1][3] = fmaf(a.y, b.w, acc[1][3]);
            acc[2][0] = fmaf(a.z, b.x, acc[2][0]);
            acc[2][1] = fmaf(a.z, b.y, acc[2][1]);
            acc[2][2] = fmaf(a.z, b.z, acc[2][2]);
            acc[2][3] = fmaf(a.z, b.w, acc[2][3]);
            acc[3][0] = fmaf(a.w, b.x, acc[3][0]);
            acc[3][1] = fmaf(a.w, b.y, acc[3][1]);
            acc[3][2] = fmaf(a.w, b.z, acc[3][2]);
            acc[3][3] = fmaf(a.w, b.w, acc[3][3]);
        }
        __syncthreads();
    }

    #pragma unroll
    for (int i = 0; i < 4; ++i) {
        int row = bm + (ty << 2) + i;
        if (row >= M) continue;
        #pragma unroll
        for (int j = 0; j < 4; ++j) {
            int col = bn + (tx << 2) + j;
            float v = acc[i][j];
            if (BIAS) v += bias[col];
            if (RELU) v = fmaxf(v, 0.f);
            C[(size_t)row * NC + col] = v;
        }
    }
}

// ---------------- batchnorm ----------------
__global__ __launch_bounds__(256) void zero_stats_k(float* __restrict__ s) {
    int i = blockIdx.x * 256 + threadIdx.x;        // grid 8 -> 2048 = 2*Hc
    s[i] = 0.f;
}

__global__ __launch_bounds__(256)
void bn_stats_k(const float* __restrict__ x, float* __restrict__ s1, float* __restrict__ s2)
{
    int c = blockIdx.x * 256 + threadIdx.x;        // < Hc
    int r0 = blockIdx.y * 250;                     // 80 chunks * 250 = 20000
    float s = 0.f, q = 0.f;
    const float* p = x + (size_t)r0 * Hc + c;
    for (int r = 0; r < 250; ++r) {
        float v = p[(size_t)r * Hc];
        s += v;
        q = fmaf(v, v, q);
    }
    atomicAdd(&s1[c], s);
    atomicAdd(&s2[c], q);
}

__global__ __launch_bounds__(256)
void bn_finalize_k(float* __restrict__ s1, float* __restrict__ s2,
                   const float* __restrict__ g, const float* __restrict__ beta)
{
    int c = blockIdx.x * 256 + threadIdx.x;
    if (c >= Hc) return;
    float mean = s1[c] * (1.0f / Nn);
    float var  = s2[c] * (1.0f / Nn) - mean * mean;
    float rstd = rsqrtf(var + EPSc);
    float sc = g[c] * rstd;
    s1[c] = sc;                       // scale
    s2[c] = beta[c] - mean * sc;      // shift
}

__global__ __launch_bounds__(256)
void bn_apply_k(float4* __restrict__ x, const float* __restrict__ scale,
                const float* __restrict__ shift)
{
    int idx = blockIdx.x * 256 + threadIdx.x;      // < Nn*Hc/4 (exact grid)
    int c4 = (idx & (Hc / 4 - 1)) << 2;
    float4 sc = *(const float4*)(scale + c4);
    float4 sh = *(const float4*)(shift + c4);
    float4 v = x[idx];
    v.x = fmaxf(fmaf(v.x, sc.x, sh.x), 0.f);
    v.y = fmaxf(fmaf(v.y, sc.y, sh.y), 0.f);
    v.z = fmaxf(fmaf(v.z, sc.z, sh.z), 0.f);
    v.w = fmaxf(fmaf(v.w, sc.w, sh.w), 0.f);
    x[idx] = v;
}

// ---------------- head: out = log_softmax(z @ Wl2 + bl2) ----------------
__global__ __launch_bounds__(256)
void head_k(const float* __restrict__ z, const float* __restrict__ Wl2,
            const float* __restrict__ bl2, float* __restrict__ out)
{
    int wave = threadIdx.x >> 6;
    int lane = threadIdx.x & 63;
    int node = blockIdx.x * 4 + wave;              // grid = Nn/4 exact
    const float4 zv = *(const float4*)(z + (size_t)node * HMc + lane * 4);
    float p[DOUTc];
    #pragma unroll
    for (int j = 0; j < DOUTc; ++j) p[j] = 0.f;
    const float zz[4] = {zv.x, zv.y, zv.z, zv.w};
    #pragma unroll
    for (int i = 0; i < 4; ++i) {
        int k = lane * 4 + i;
        const float* wrow = Wl2 + (size_t)k * DOUTc;
        #pragma unroll
        for (int j = 0; j < DOUTc; ++j) p[j] = fmaf(zz[i], wrow[j], p[j]);
    }
    #pragma unroll
    for (int j = 0; j < DOUTc; ++j) {
        #pragma unroll
        for (int off = 32; off > 0; off >>= 1) p[j] += __shfl_down(p[j], off, 64);
    }
    if (lane == 0) {
        float v[DOUTc];
        float m = -1e30f;
        #pragma unroll
        for (int j = 0; j < DOUTc; ++j) { v[j] = p[j] + bl2[j]; m = fmaxf(m, v[j]); }
        float s = 0.f;
        #pragma unroll
        for (int j = 0; j < DOUTc; ++j) s += expf(v[j] - m);
        float ls = logf(s) + m;
        #pragma unroll
        for (int j = 0; j < DOUTc; ++j) out[(size_t)node * DOUTc + j] = v[j] - ls;
    }
}

// ---------------- launch ----------------
extern "C" void kernel_launch(void* const* d_in, const int* in_sizes, int n_in,
                              void* d_out, int out_size, void* d_ws, size_t ws_size,
                              hipStream_t stream)
{
    (void)in_sizes; (void)n_in; (void)out_size; (void)ws_size;
    const float* x    = (const float*)d_in[0];
    const int*   ei   = (const int*)d_in[1];
    const float* ew   = (const float*)d_in[2];
    const float* W1   = (const float*)d_in[3];
    // b1 = d_in[4]: cancels under batchnorm mean-subtraction
    const float* gam1 = (const float*)d_in[5];
    const float* bet1 = (const float*)d_in[6];
    const float* W2   = (const float*)d_in[7];
    // b2 = d_in[8]: cancels
    const float* gam2 = (const float*)d_in[9];
    const float* bet2 = (const float*)d_in[10];
    const float* Wl1  = (const float*)d_in[11];
    const float* bl1  = (const float*)d_in[12];
    const float* Wl2  = (const float*)d_in[13];
    const float* bl2  = (const float*)d_in[14];
    float* out = (float*)d_out;

    float* bufA = (float*)d_ws;                    // Nn*Hc
    float* bufB = bufA + (size_t)Nn * Hc;          // Nn*Hc
    float* dinv = bufB + (size_t)Nn * Hc;          // Nn
    float* s1   = dinv + Nn;                       // Hc
    float* s2   = s1 + Hc;                         // Hc
    int*   cnt      = (int*)(s2 + Hc);             // Nn
    int*   row_ptr  = cnt + Nn;                    // Nn+1
    int*   cursor   = row_ptr + Nn + 1;            // Nn
    int*   csr_src  = cursor + Nn;                 // Ne
    float* csr_coef = (float*)(csr_src + Ne);      // Ne

    const int* srcv = ei;
    const int* dstv = ei + Ne;

    const int EW4 = Nn * Hc / 4 / 256;             // 20000 blocks for elementwise f4

    // ---- build dinv + CSR (by dst) once; shared by both layers ----
    deg_init_k<<<(Nn + 255) / 256, 256, 0, stream>>>(dinv, cnt);
    deg_edge_k<<<(Ne + 255) / 256, 256, 0, stream>>>(ew, dstv, dinv, cnt);
    dinv_k<<<(Nn + 255) / 256, 256, 0, stream>>>(dinv);
    scan_k<<<1, 1024, 0, stream>>>(cnt, row_ptr, cursor);
    csr_fill_k<<<(Ne + 255) / 256, 256, 0, stream>>>(srcv, dstv, ew, dinv, cursor,
                                                     csr_src, csr_coef);

    dim3 ggrid(Hc / 64, (Nn + 63) / 64);

    // layer 1
    gemm_k<Hc, DIN, false, false><<<ggrid, 256, 0, stream>>>(x, W1, nullptr, bufA, Nn);
    spmm_k<<<Nn, 256, 0, stream>>>((const float4*)bufA, row_ptr, csr_src, csr_coef,
                                   dinv, (float4*)bufB);
    zero_stats_k<<<8, 256, 0, stream>>>(s1);
    bn_stats_k<<<dim3(Hc / 256, 80), 256, 0, stream>>>(bufB, s1, s2);
    bn_finalize_k<<<Hc / 256, 256, 0, stream>>>(s1, s2, gam1, bet1);
    bn_apply_k<<<EW4, 256, 0, stream>>>((float4*)bufB, s1, s2);

    // layer 2
    gemm_k<Hc, Hc, false, false><<<ggrid, 256, 0, stream>>>(bufB, W2, nullptr, bufA, Nn);
    spmm_k<<<Nn, 256, 0, stream>>>((const float4*)bufA, row_ptr, csr_src, csr_coef,
                                   dinv, (float4*)bufB);
    zero_stats_k<<<8, 256, 0, stream>>>(s1);
    bn_stats_k<<<dim3(Hc / 256, 80), 256, 0, stream>>>(bufB, s1, s2);
    bn_finalize_k<<<Hc / 256, 256, 0, stream>>>(s1, s2, gam2, bet2);
    bn_apply_k<<<EW4, 256, 0, stream>>>((float4*)bufB, s1, s2);

    // MLP head: z = relu(h @ Wl1 + bl1) into bufA (reuse), then fused GEMM4+log_softmax
    gemm_k<HMc, Hc, true, true><<<dim3(HMc / 64, (Nn + 63) / 64), 256, 0, stream>>>(bufB, Wl1, bl1, bufA, Nn);
    head_k<<<Nn / 4, 256, 0, stream>>>(bufA, Wl2, bl2, out);
}

// Round 3
// 814.753 us; speedup vs baseline: 11.5048x; 1.8029x over previous
//
#include <hip/hip_runtime.h>
#include <math.h>

static constexpr int Nn  = 20000;
static constexpr int Ne  = 320000;
static constexpr int DIN = 128;
static constexpr int DOUTc = 10;
static constexpr int Hc  = 1024;
static constexpr int HMc = 256;
static constexpr float EPSc = 1e-5f;

typedef __bf16 bf16_t;
typedef __bf16 bf16x8 __attribute__((ext_vector_type(8)));
typedef __bf16 bf16x4 __attribute__((ext_vector_type(4)));
typedef float  f32x4  __attribute__((ext_vector_type(4)));

__device__ __forceinline__ void gload_lds16(const bf16_t* g, bf16_t* lds) {
    __builtin_amdgcn_global_load_lds(
        (const __attribute__((address_space(1))) void*)g,
        (__attribute__((address_space(3))) void*)lds, 16, 0, 0);
}

// ---------------- degree / count init ----------------
__global__ __launch_bounds__(256) void deg_init_k(float* __restrict__ deg, int* __restrict__ cnt) {
    int i = blockIdx.x * 256 + threadIdx.x;
    if (i < Nn) { deg[i] = 1.0f; cnt[i] = 0; }     // self-loop weight 1
}

__global__ __launch_bounds__(256)
void deg_edge_k(const float* __restrict__ w, const int* __restrict__ dstv,
                float* __restrict__ deg, int* __restrict__ cnt) {
    int e = blockIdx.x * 256 + threadIdx.x;
    if (e < Ne) {
        int d = dstv[e];
        atomicAdd(&deg[d], w[e]);
        atomicAdd(&cnt[d], 1);
    }
}

__global__ __launch_bounds__(256) void dinv_k(float* __restrict__ deg) {
    int i = blockIdx.x * 256 + threadIdx.x;
    if (i < Nn) deg[i] = rsqrtf(deg[i]);  // deg >= 1 always
}

// ---------------- single-block exclusive scan over cnt -> row_ptr, cursor ----------------
__global__ __launch_bounds__(1024)
void scan_k(const int* __restrict__ cnt, int* __restrict__ row_ptr, int* __restrict__ cursor)
{
    __shared__ int sm[1024];
    __shared__ int carry_s;
    int tid = threadIdx.x;
    if (tid == 0) carry_s = 0;
    __syncthreads();
    for (int base = 0; base < Nn; base += 1024) {
        int i = base + tid;
        int v = (i < Nn) ? cnt[i] : 0;
        sm[tid] = v;
        __syncthreads();
        #pragma unroll
        for (int off = 1; off < 1024; off <<= 1) {
            int t = (tid >= off) ? sm[tid - off] : 0;
            __syncthreads();
            sm[tid] += t;
            __syncthreads();
        }
        int incl = sm[tid];
        int carry = carry_s;
        if (i < Nn) {
            int excl = carry + incl - v;
            row_ptr[i] = excl;
            cursor[i]  = excl;
        }
        __syncthreads();
        if (tid == 1023) carry_s = carry + incl;
        __syncthreads();
    }
    if (tid == 0) row_ptr[Nn] = Ne;
}

// ---------------- CSR fill (coeff precomputed) ----------------
__global__ __launch_bounds__(256)
void csr_fill_k(const int* __restrict__ srcv, const int* __restrict__ dstv,
                const float* __restrict__ w, const float* __restrict__ dinv,
                int* __restrict__ cursor, int* __restrict__ csr_src,
                float* __restrict__ csr_coeff)
{
    int e = blockIdx.x * 256 + threadIdx.x;
    if (e >= Ne) return;
    int s = srcv[e], d = dstv[e];
    int pos = atomicAdd(&cursor[d], 1);
    csr_src[pos]   = s;
    csr_coeff[pos] = dinv[s] * w[e] * dinv[d];
}

// ---------------- gather SpMM: out[d] = dinv[d]^2*h[d] + sum_e coeff*h[src] ----------------
__global__ __launch_bounds__(256)
void spmm_k(const float4* __restrict__ h4, const int* __restrict__ row_ptr,
            const int* __restrict__ csr_src, const float* __restrict__ csr_coeff,
            const float* __restrict__ dinv, float4* __restrict__ out4)
{
    int d = blockIdx.x;                 // grid = Nn
    int f = threadIdx.x;                // 0..255, owns float4 (Hc/4 == 256)
    float c = dinv[d]; c = c * c;
    float4 acc = h4[(size_t)d * 256 + f];
    acc.x *= c; acc.y *= c; acc.z *= c; acc.w *= c;
    int beg = row_ptr[d], end = row_ptr[d + 1];
    for (int j = beg; j < end; ++j) {
        int   s  = csr_src[j];
        float cf = csr_coeff[j];
        float4 v = h4[(size_t)s * 256 + f];
        acc.x = fmaf(cf, v.x, acc.x);
        acc.y = fmaf(cf, v.y, acc.y);
        acc.z = fmaf(cf, v.z, acc.z);
        acc.w = fmaf(cf, v.w, acc.w);
    }
    out4[(size_t)d * 256 + f] = acc;
}

// ---------------- weight transpose + convert: Wt[n][k] = bf16(W[k][n]) ----------------
template<int RK, int CN>   // W is RK x CN fp32; Wt is CN x RK bf16
__global__ __launch_bounds__(256)
void transpose_bf16_k(const float* __restrict__ W, bf16_t* __restrict__ Wt)
{
    __shared__ float tile[32][33];
    int bx = blockIdx.x * 32;  // input col base
    int by = blockIdx.y * 32;  // input row base
    int tx = threadIdx.x & 31, ty = threadIdx.x >> 5;  // ty 0..7
    #pragma unroll
    for (int p = 0; p < 32; p += 8)
        tile[ty + p][tx] = W[(size_t)(by + ty + p) * CN + bx + tx];
    __syncthreads();
    #pragma unroll
    for (int p = 0; p < 32; p += 8)
        Wt[(size_t)(bx + ty + p) * RK + by + tx] = (bf16_t)tile[tx][ty + p];
}

// ---------------- fp32 -> bf16 convert (x) ----------------
__global__ __launch_bounds__(256)
void cvt_bf16_k(const float4* __restrict__ in, bf16x4* __restrict__ out, int n4)
{
    int i = blockIdx.x * 256 + threadIdx.x;
    if (i >= n4) return;
    float4 v = in[i];
    bf16x4 o = { (bf16_t)v.x, (bf16_t)v.y, (bf16_t)v.z, (bf16_t)v.w };
    out[i] = o;
}

// ---------------- bf16 MFMA GEMM: C[M x NC] = A[M x KD] @ Bt[NC x KD]^T ----------------
// 128x128 tile, 4 waves in 2x2, each wave 64x64 via 4x4 of 16x16x32 MFMA.
// LDS layout (per tile, per row m of 32 bf16): chunk q of 8 elems stored at
// byte offset m*64 + (q ^ ((m>>1)&3))*16  -> 2-way-max bank aliasing (free).
template<int NC, int KD, bool BIAS, bool RELU>
__global__ __launch_bounds__(256)
void gemm_bf16_k(const bf16_t* __restrict__ A, const bf16_t* __restrict__ Bt,
                 const float* __restrict__ bias, float* __restrict__ C, int M)
{
    __shared__ __align__(16) bf16_t Asm[128 * 32];
    __shared__ __align__(16) bf16_t Bsm[128 * 32];
    const int tid  = threadIdx.x;
    const int w    = tid >> 6;
    const int lane = tid & 63;
    const int bm = blockIdx.y * 128, bn = blockIdx.x * 128;
    const int l15 = lane & 15, quad = lane >> 4;
    const int wm = (w & 1) * 64, wn = (w >> 1) * 64;
    const int swz = quad ^ ((l15 >> 1) & 3);

    // staging: wave w owns tile rows [w*32, w*32+32), two 16-row chunks
    const int srow = lane >> 2;                              // row within chunk
    const int scol = 8 * ((lane & 3) ^ ((lane >> 3) & 3));   // k offset within 32
    const int c0 = w * 32;
    int ga0 = bm + c0 + srow;       if (ga0 >= M) ga0 = M - 1;
    int ga1 = bm + c0 + 16 + srow;  if (ga1 >= M) ga1 = M - 1;
    const bf16_t* gA0 = A + (size_t)ga0 * KD + scol;
    const bf16_t* gA1 = A + (size_t)ga1 * KD + scol;
    const bf16_t* gB0 = Bt + (size_t)(bn + c0 + srow) * KD + scol;
    const bf16_t* gB1 = gB0 + (size_t)16 * KD;
    bf16_t* lA0 = Asm + (c0 +  0) * 32;
    bf16_t* lA1 = Asm + (c0 + 16) * 32;
    bf16_t* lB0 = Bsm + (c0 +  0) * 32;
    bf16_t* lB1 = Bsm + (c0 + 16) * 32;

    // fragment read bases
    const bf16_t* pA = Asm + (wm + l15) * 32 + swz * 8;
    const bf16_t* pB = Bsm + (wn + l15) * 32 + swz * 8;

    f32x4 acc[4][4] = {};

    for (int k0 = 0; k0 < KD; k0 += 32) {
        gload_lds16(gA0 + k0, lA0);
        gload_lds16(gA1 + k0, lA1);
        gload_lds16(gB0 + k0, lB0);
        gload_lds16(gB1 + k0, lB1);
        __syncthreads();
        bf16x8 af[4], bfr[4];
        #pragma unroll
        for (int t = 0; t < 4; ++t) {
            af[t]  = *(const bf16x8*)(pA + t * 16 * 32);
            bfr[t] = *(const bf16x8*)(pB + t * 16 * 32);
        }
        #pragma unroll
        for (int mt = 0; mt < 4; ++mt)
            #pragma unroll
            for (int nt = 0; nt < 4; ++nt)
                acc[mt][nt] = __builtin_amdgcn_mfma_f32_16x16x32_bf16(
                    af[mt], bfr[nt], acc[mt][nt], 0, 0, 0);
        __syncthreads();
    }

    // epilogue: D row = quad*4 + r, col = l15 within each 16x16 tile
    #pragma unroll
    for (int mt = 0; mt < 4; ++mt) {
        #pragma unroll
        for (int r = 0; r < 4; ++r) {
            int row = bm + wm + mt * 16 + quad * 4 + r;
            if (row >= M) continue;
            #pragma unroll
            for (int nt = 0; nt < 4; ++nt) {
                int col = bn + wn + nt * 16 + l15;
                float v = acc[mt][nt][r];
                if (BIAS) v += bias[col];
                if (RELU) v = fmaxf(v, 0.f);
                C[(size_t)row * NC + col] = v;
            }
        }
    }
}

// ---------------- batchnorm ----------------
__global__ __launch_bounds__(256) void zero_stats_k(float* __restrict__ s) {
    int i = blockIdx.x * 256 + threadIdx.x;        // grid 8 -> 2048 = 2*Hc
    s[i] = 0.f;
}

__global__ __launch_bounds__(256)
void bn_stats_k(const float* __restrict__ x, float* __restrict__ s1, float* __restrict__ s2)
{
    int c = blockIdx.x * 256 + threadIdx.x;        // < Hc
    int r0 = blockIdx.y * 250;                     // 80 chunks * 250 = 20000
    float s = 0.f, q = 0.f;
    const float* p = x + (size_t)r0 * Hc + c;
    for (int r = 0; r < 250; ++r) {
        float v = p[(size_t)r * Hc];
        s += v;
        q = fmaf(v, v, q);
    }
    atomicAdd(&s1[c], s);
    atomicAdd(&s2[c], q);
}

__global__ __launch_bounds__(256)
void bn_finalize_k(float* __restrict__ s1, float* __restrict__ s2,
                   const float* __restrict__ g, const float* __restrict__ beta)
{
    int c = blockIdx.x * 256 + threadIdx.x;
    if (c >= Hc) return;
    float mean = s1[c] * (1.0f / Nn);
    float var  = s2[c] * (1.0f / Nn) - mean * mean;
    float rstd = rsqrtf(var + EPSc);
    float sc = g[c] * rstd;
    s1[c] = sc;                       // scale
    s2[c] = beta[c] - mean * sc;      // shift
}

// BN + ReLU, emitting bf16 (feeds the next MFMA GEMM)
__global__ __launch_bounds__(256)
void bn_apply_k(const float4* __restrict__ x, const float* __restrict__ scale,
                const float* __restrict__ shift, bf16x4* __restrict__ out)
{
    int idx = blockIdx.x * 256 + threadIdx.x;      // < Nn*Hc/4 (exact grid)
    int c4 = (idx & (Hc / 4 - 1)) << 2;
    float4 sc = *(const float4*)(scale + c4);
    float4 sh = *(const float4*)(shift + c4);
    float4 v = x[idx];
    bf16x4 o = { (bf16_t)fmaxf(fmaf(v.x, sc.x, sh.x), 0.f),
                 (bf16_t)fmaxf(fmaf(v.y, sc.y, sh.y), 0.f),
                 (bf16_t)fmaxf(fmaf(v.z, sc.z, sh.z), 0.f),
                 (bf16_t)fmaxf(fmaf(v.w, sc.w, sh.w), 0.f) };
    out[idx] = o;
}

// ---------------- head: out = log_softmax(z @ Wl2 + bl2) ----------------
__global__ __launch_bounds__(256)
void head_k(const float* __restrict__ z, const float* __restrict__ Wl2,
            const float* __restrict__ bl2, float* __restrict__ out)
{
    int wave = threadIdx.x >> 6;
    int lane = threadIdx.x & 63;
    int node = blockIdx.x * 4 + wave;              // grid = Nn/4 exact
    const float4 zv = *(const float4*)(z + (size_t)node * HMc + lane * 4);
    float p[DOUTc];
    #pragma unroll
    for (int j = 0; j < DOUTc; ++j) p[j] = 0.f;
    const float zz[4] = {zv.x, zv.y, zv.z, zv.w};
    #pragma unroll
    for (int i = 0; i < 4; ++i) {
        int k = lane * 4 + i;
        const float* wrow = Wl2 + (size_t)k * DOUTc;
        #pragma unroll
        for (int j = 0; j < DOUTc; ++j) p[j] = fmaf(zz[i], wrow[j], p[j]);
    }
    #pragma unroll
    for (int j = 0; j < DOUTc; ++j) {
        #pragma unroll
        for (int off = 32; off > 0; off >>= 1) p[j] += __shfl_down(p[j], off, 64);
    }
    if (lane == 0) {
        float v[DOUTc];
        float m = -1e30f;
        #pragma unroll
        for (int j = 0; j < DOUTc; ++j) { v[j] = p[j] + bl2[j]; m = fmaxf(m, v[j]); }
        float s = 0.f;
        #pragma unroll
        for (int j = 0; j < DOUTc; ++j) s += expf(v[j] - m);
        float ls = logf(s) + m;
        #pragma unroll
        for (int j = 0; j < DOUTc; ++j) out[(size_t)node * DOUTc + j] = v[j] - ls;
    }
}

// ---------------- launch ----------------
extern "C" void kernel_launch(void* const* d_in, const int* in_sizes, int n_in,
                              void* d_out, int out_size, void* d_ws, size_t ws_size,
                              hipStream_t stream)
{
    (void)in_sizes; (void)n_in; (void)out_size; (void)ws_size;
    const float* x    = (const float*)d_in[0];
    const int*   ei   = (const int*)d_in[1];
    const float* ew   = (const float*)d_in[2];
    const float* W1   = (const float*)d_in[3];
    // b1 = d_in[4]: cancels under batchnorm mean-subtraction
    const float* gam1 = (const float*)d_in[5];
    const float* bet1 = (const float*)d_in[6];
    const float* W2   = (const float*)d_in[7];
    // b2 = d_in[8]: cancels
    const float* gam2 = (const float*)d_in[9];
    const float* bet2 = (const float*)d_in[10];
    const float* Wl1  = (const float*)d_in[11];
    const float* bl1  = (const float*)d_in[12];
    const float* Wl2  = (const float*)d_in[13];
    const float* bl2  = (const float*)d_in[14];
    float* out = (float*)d_out;

    float* bufA = (float*)d_ws;                    // Nn*Hc f32 (GEMM out)
    float* bufB = bufA + (size_t)Nn * Hc;          // Nn*Hc f32 (SpMM out)
    float* dinv = bufB + (size_t)Nn * Hc;          // Nn
    float* s1   = dinv + Nn;                       // Hc
    float* s2   = s1 + Hc;                         // Hc
    int*   cnt      = (int*)(s2 + Hc);             // Nn
    int*   row_ptr  = cnt + Nn;                    // Nn+16 (padded for alignment)
    int*   cursor   = row_ptr + Nn + 16;           // Nn
    int*   csr_src  = cursor + Nn;                 // Ne
    float* csr_coef = (float*)(csr_src + Ne);      // Ne
    bf16_t* xb   = (bf16_t*)(csr_coef + Ne);       // Nn*DIN   (16B aligned)
    bf16_t* hbf  = xb + (size_t)Nn * DIN;          // Nn*Hc
    bf16_t* W1t  = hbf + (size_t)Nn * Hc;          // Hc*DIN  (= W1^T)
    bf16_t* W2t  = W1t + (size_t)Hc * DIN;         // Hc*Hc   (= W2^T)
    bf16_t* Wl1t = W2t + (size_t)Hc * Hc;          // HMc*Hc  (= Wl1^T)

    const int* srcv = ei;
    const int* dstv = ei + Ne;

    const int EW4 = Nn * Hc / 4 / 256;             // 20000 blocks for elementwise f4

    // ---- one-time per launch: dinv + CSR + bf16 weights/x ----
    deg_init_k<<<(Nn + 255) / 256, 256, 0, stream>>>(dinv, cnt);
    deg_edge_k<<<(Ne + 255) / 256, 256, 0, stream>>>(ew, dstv, dinv, cnt);
    dinv_k<<<(Nn + 255) / 256, 256, 0, stream>>>(dinv);
    scan_k<<<1, 1024, 0, stream>>>(cnt, row_ptr, cursor);
    csr_fill_k<<<(Ne + 255) / 256, 256, 0, stream>>>(srcv, dstv, ew, dinv, cursor,
                                                     csr_src, csr_coef);
    transpose_bf16_k<DIN, Hc><<<dim3(Hc / 32, DIN / 32), 256, 0, stream>>>(W1, W1t);
    transpose_bf16_k<Hc, Hc><<<dim3(Hc / 32, Hc / 32), 256, 0, stream>>>(W2, W2t);
    transpose_bf16_k<Hc, HMc><<<dim3(HMc / 32, Hc / 32), 256, 0, stream>>>(Wl1, Wl1t);
    cvt_bf16_k<<<(Nn * DIN / 4 + 255) / 256, 256, 0, stream>>>(
        (const float4*)x, (bf16x4*)xb, Nn * DIN / 4);

    const int MB = (Nn + 127) / 128;               // 157 row-blocks

    // layer 1
    gemm_bf16_k<Hc, DIN, false, false><<<dim3(Hc / 128, MB), 256, 0, stream>>>(
        xb, W1t, nullptr, bufA, Nn);
    spmm_k<<<Nn, 256, 0, stream>>>((const float4*)bufA, row_ptr, csr_src, csr_coef,
                                   dinv, (float4*)bufB);
    zero_stats_k<<<8, 256, 0, stream>>>(s1);
    bn_stats_k<<<dim3(Hc / 256, 80), 256, 0, stream>>>(bufB, s1, s2);
    bn_finalize_k<<<Hc / 256, 256, 0, stream>>>(s1, s2, gam1, bet1);
    bn_apply_k<<<EW4, 256, 0, stream>>>((const float4*)bufB, s1, s2, (bf16x4*)hbf);

    // layer 2
    gemm_bf16_k<Hc, Hc, false, false><<<dim3(Hc / 128, MB), 256, 0, stream>>>(
        hbf, W2t, nullptr, bufA, Nn);
    spmm_k<<<Nn, 256, 0, stream>>>((const float4*)bufA, row_ptr, csr_src, csr_coef,
                                   dinv, (float4*)bufB);
    zero_stats_k<<<8, 256, 0, stream>>>(s1);
    bn_stats_k<<<dim3(Hc / 256, 80), 256, 0, stream>>>(bufB, s1, s2);
    bn_finalize_k<<<Hc / 256, 256, 0, stream>>>(s1, s2, gam2, bet2);
    bn_apply_k<<<EW4, 256, 0, stream>>>((const float4*)bufB, s1, s2, (bf16x4*)hbf);

    // MLP head: z = relu(h @ Wl1 + bl1) (fp32 out), then fused GEMM+log_softmax
    gemm_bf16_k<HMc, Hc, true, true><<<dim3(HMc / 128, MB), 256, 0, stream>>>(
        hbf, Wl1t, bl1, bufA, Nn);
    head_k<<<Nn / 4, 256, 0, stream>>>(bufA, Wl2, bl2, out);
}

// Round 4
// 609.498 us; speedup vs baseline: 15.3791x; 1.3368x over previous
//
#include <hip/hip_runtime.h>
#include <math.h>

static constexpr int Nn  = 20000;
static constexpr int Ne  = 320000;
static constexpr int DIN = 128;
static constexpr int DOUTc = 10;
static constexpr int Hc  = 1024;
static constexpr int HMc = 256;
static constexpr float EPSc = 1e-5f;

typedef __bf16 bf16_t;
typedef __bf16 bf16x8 __attribute__((ext_vector_type(8)));
typedef __bf16 bf16x4 __attribute__((ext_vector_type(4)));
typedef float  f32x4  __attribute__((ext_vector_type(4)));

__device__ __forceinline__ void gload_lds16(const bf16_t* g, bf16_t* lds) {
    __builtin_amdgcn_global_load_lds(
        (const __attribute__((address_space(1))) void*)g,
        (__attribute__((address_space(3))) void*)lds, 16, 0, 0);
}

// ---------------- degree / count init ----------------
__global__ __launch_bounds__(256) void deg_init_k(float* __restrict__ deg, int* __restrict__ cnt) {
    int i = blockIdx.x * 256 + threadIdx.x;
    if (i < Nn) { deg[i] = 1.0f; cnt[i] = 0; }     // self-loop weight 1
}

__global__ __launch_bounds__(256)
void deg_edge_k(const float* __restrict__ w, const int* __restrict__ dstv,
                float* __restrict__ deg, int* __restrict__ cnt) {
    int e = blockIdx.x * 256 + threadIdx.x;
    if (e < Ne) {
        int d = dstv[e];
        atomicAdd(&deg[d], w[e]);
        atomicAdd(&cnt[d], 1);
    }
}

__global__ __launch_bounds__(256) void dinv_k(float* __restrict__ deg) {
    int i = blockIdx.x * 256 + threadIdx.x;
    if (i < Nn) deg[i] = rsqrtf(deg[i]);  // deg >= 1 always
}

// ---------------- single-block exclusive scan over cnt -> row_ptr, cursor ----------------
__global__ __launch_bounds__(1024)
void scan_k(const int* __restrict__ cnt, int* __restrict__ row_ptr, int* __restrict__ cursor)
{
    __shared__ int sm[1024];
    __shared__ int carry_s;
    int tid = threadIdx.x;
    if (tid == 0) carry_s = 0;
    __syncthreads();
    for (int base = 0; base < Nn; base += 1024) {
        int i = base + tid;
        int v = (i < Nn) ? cnt[i] : 0;
        sm[tid] = v;
        __syncthreads();
        #pragma unroll
        for (int off = 1; off < 1024; off <<= 1) {
            int t = (tid >= off) ? sm[tid - off] : 0;
            __syncthreads();
            sm[tid] += t;
            __syncthreads();
        }
        int incl = sm[tid];
        int carry = carry_s;
        if (i < Nn) {
            int excl = carry + incl - v;
            row_ptr[i] = excl;
            cursor[i]  = excl;
        }
        __syncthreads();
        if (tid == 1023) carry_s = carry + incl;
        __syncthreads();
    }
    if (tid == 0) row_ptr[Nn] = Ne;
}

// ---------------- CSR fill (coeff precomputed) ----------------
__global__ __launch_bounds__(256)
void csr_fill_k(const int* __restrict__ srcv, const int* __restrict__ dstv,
                const float* __restrict__ w, const float* __restrict__ dinv,
                int* __restrict__ cursor, int* __restrict__ csr_src,
                float* __restrict__ csr_coeff)
{
    int e = blockIdx.x * 256 + threadIdx.x;
    if (e >= Ne) return;
    int s = srcv[e], d = dstv[e];
    int pos = atomicAdd(&cursor[d], 1);
    csr_src[pos]   = s;
    csr_coeff[pos] = dinv[s] * w[e] * dinv[d];
}

// ---------------- gather SpMM (bf16 rows): out[d] = dinv[d]^2*h[d] + sum coeff*h[src] ----------------
// 2 nodes per block; 128 lanes per node, each lane owns 8 bf16 (16 B).
__global__ __launch_bounds__(256)
void spmm_bf16_k(const bf16x8* __restrict__ h8, const int* __restrict__ row_ptr,
                 const int* __restrict__ csr_src, const float* __restrict__ csr_coeff,
                 const float* __restrict__ dinv, float4* __restrict__ out4)
{
    int d = blockIdx.x * 2 + (threadIdx.x >> 7);
    int f = threadIdx.x & 127;                     // Hc/8 == 128
    float c = dinv[d]; c = c * c;
    bf16x8 hv = h8[(size_t)d * 128 + f];
    float acc[8];
    #pragma unroll
    for (int i = 0; i < 8; ++i) acc[i] = c * (float)hv[i];
    int beg = row_ptr[d], end = row_ptr[d + 1];
    for (int j = beg; j < end; ++j) {
        int   s  = csr_src[j];
        float cf = csr_coeff[j];
        bf16x8 v = h8[(size_t)s * 128 + f];
        #pragma unroll
        for (int i = 0; i < 8; ++i) acc[i] = fmaf(cf, (float)v[i], acc[i]);
    }
    float4 o0 = {acc[0], acc[1], acc[2], acc[3]};
    float4 o1 = {acc[4], acc[5], acc[6], acc[7]};
    out4[(size_t)d * 256 + 2 * f]     = o0;
    out4[(size_t)d * 256 + 2 * f + 1] = o1;
}

// ---------------- weight transpose + convert: Wt[n][k] = bf16(W[k][n]) ----------------
template<int RK, int CN>   // W is RK x CN fp32; Wt is CN x RK bf16
__global__ __launch_bounds__(256)
void transpose_bf16_k(const float* __restrict__ W, bf16_t* __restrict__ Wt)
{
    __shared__ float tile[32][33];
    int bx = blockIdx.x * 32;  // input col base
    int by = blockIdx.y * 32;  // input row base
    int tx = threadIdx.x & 31, ty = threadIdx.x >> 5;  // ty 0..7
    #pragma unroll
    for (int p = 0; p < 32; p += 8)
        tile[ty + p][tx] = W[(size_t)(by + ty + p) * CN + bx + tx];
    __syncthreads();
    #pragma unroll
    for (int p = 0; p < 32; p += 8)
        Wt[(size_t)(bx + ty + p) * RK + by + tx] = (bf16_t)tile[tx][ty + p];
}

// ---------------- fp32 -> bf16 convert (x) ----------------
__global__ __launch_bounds__(256)
void cvt_bf16_k(const float4* __restrict__ in, bf16x4* __restrict__ out, int n4)
{
    int i = blockIdx.x * 256 + threadIdx.x;
    if (i >= n4) return;
    float4 v = in[i];
    bf16x4 o = { (bf16_t)v.x, (bf16_t)v.y, (bf16_t)v.z, (bf16_t)v.w };
    out[i] = o;
}

// ---------------- bf16 MFMA GEMM: C[M x NC] = A[M x KD] @ Bt[NC x KD]^T ----------------
// 128x128 tile, 4 waves in 2x2, each wave 64x64 via 4x4 of 16x16x32 MFMA.
// OUTBF: store bf16 (for feeding SpMM); else fp32.
template<int NC, int KD, bool BIAS, bool RELU, bool OUTBF>
__global__ __launch_bounds__(256)
void gemm_bf16_k(const bf16_t* __restrict__ A, const bf16_t* __restrict__ Bt,
                 const float* __restrict__ bias, void* __restrict__ Cv, int M)
{
    __shared__ __align__(16) bf16_t Asm[128 * 32];
    __shared__ __align__(16) bf16_t Bsm[128 * 32];
    const int tid  = threadIdx.x;
    const int w    = tid >> 6;
    const int lane = tid & 63;
    const int bm = blockIdx.y * 128, bn = blockIdx.x * 128;
    const int l15 = lane & 15, quad = lane >> 4;
    const int wm = (w & 1) * 64, wn = (w >> 1) * 64;
    const int swz = quad ^ ((l15 >> 1) & 3);

    // staging: wave w owns tile rows [w*32, w*32+32), two 16-row chunks
    const int srow = lane >> 2;                              // row within chunk
    const int scol = 8 * ((lane & 3) ^ ((lane >> 3) & 3));   // k offset within 32
    const int c0 = w * 32;
    int ga0 = bm + c0 + srow;       if (ga0 >= M) ga0 = M - 1;
    int ga1 = bm + c0 + 16 + srow;  if (ga1 >= M) ga1 = M - 1;
    const bf16_t* gA0 = A + (size_t)ga0 * KD + scol;
    const bf16_t* gA1 = A + (size_t)ga1 * KD + scol;
    const bf16_t* gB0 = Bt + (size_t)(bn + c0 + srow) * KD + scol;
    const bf16_t* gB1 = gB0 + (size_t)16 * KD;
    bf16_t* lA0 = Asm + (c0 +  0) * 32;
    bf16_t* lA1 = Asm + (c0 + 16) * 32;
    bf16_t* lB0 = Bsm + (c0 +  0) * 32;
    bf16_t* lB1 = Bsm + (c0 + 16) * 32;

    // fragment read bases
    const bf16_t* pA = Asm + (wm + l15) * 32 + swz * 8;
    const bf16_t* pB = Bsm + (wn + l15) * 32 + swz * 8;

    f32x4 acc[4][4] = {};

    for (int k0 = 0; k0 < KD; k0 += 32) {
        gload_lds16(gA0 + k0, lA0);
        gload_lds16(gA1 + k0, lA1);
        gload_lds16(gB0 + k0, lB0);
        gload_lds16(gB1 + k0, lB1);
        __syncthreads();
        bf16x8 af[4], bfr[4];
        #pragma unroll
        for (int t = 0; t < 4; ++t) {
            af[t]  = *(const bf16x8*)(pA + t * 16 * 32);
            bfr[t] = *(const bf16x8*)(pB + t * 16 * 32);
        }
        #pragma unroll
        for (int mt = 0; mt < 4; ++mt)
            #pragma unroll
            for (int nt = 0; nt < 4; ++nt)
                acc[mt][nt] = __builtin_amdgcn_mfma_f32_16x16x32_bf16(
                    af[mt], bfr[nt], acc[mt][nt], 0, 0, 0);
        __syncthreads();
    }

    // epilogue: D row = quad*4 + r, col = l15 within each 16x16 tile
    #pragma unroll
    for (int mt = 0; mt < 4; ++mt) {
        #pragma unroll
        for (int r = 0; r < 4; ++r) {
            int row = bm + wm + mt * 16 + quad * 4 + r;
            if (row >= M) continue;
            #pragma unroll
            for (int nt = 0; nt < 4; ++nt) {
                int col = bn + wn + nt * 16 + l15;
                float v = acc[mt][nt][r];
                if (BIAS) v += bias[col];
                if (RELU) v = fmaxf(v, 0.f);
                if (OUTBF) ((bf16_t*)Cv)[(size_t)row * NC + col] = (bf16_t)v;
                else       ((float*)Cv)[(size_t)row * NC + col] = v;
            }
        }
    }
}

// ---------------- batchnorm ----------------
__global__ __launch_bounds__(256) void zero_stats_k(float* __restrict__ s) {
    int i = blockIdx.x * 256 + threadIdx.x;        // grid 8 -> 2048 = 2*Hc
    s[i] = 0.f;
}

__global__ __launch_bounds__(256)
void bn_stats_k(const float* __restrict__ x, float* __restrict__ s1, float* __restrict__ s2)
{
    int c = blockIdx.x * 256 + threadIdx.x;        // < Hc
    int r0 = blockIdx.y * 250;                     // 80 chunks * 250 = 20000
    float s = 0.f, q = 0.f;
    const float* p = x + (size_t)r0 * Hc + c;
    for (int r = 0; r < 250; ++r) {
        float v = p[(size_t)r * Hc];
        s += v;
        q = fmaf(v, v, q);
    }
    atomicAdd(&s1[c], s);
    atomicAdd(&s2[c], q);
}

__global__ __launch_bounds__(256)
void bn_finalize_k(float* __restrict__ s1, float* __restrict__ s2,
                   const float* __restrict__ g, const float* __restrict__ beta)
{
    int c = blockIdx.x * 256 + threadIdx.x;
    if (c >= Hc) return;
    float mean = s1[c] * (1.0f / Nn);
    float var  = s2[c] * (1.0f / Nn) - mean * mean;
    float rstd = rsqrtf(var + EPSc);
    float sc = g[c] * rstd;
    s1[c] = sc;                       // scale
    s2[c] = beta[c] - mean * sc;      // shift
}

// BN + ReLU, emitting bf16 (feeds the next MFMA GEMM)
__global__ __launch_bounds__(256)
void bn_apply_k(const float4* __restrict__ x, const float* __restrict__ scale,
                const float* __restrict__ shift, bf16x4* __restrict__ out)
{
    int idx = blockIdx.x * 256 + threadIdx.x;      // < Nn*Hc/4 (exact grid)
    int c4 = (idx & (Hc / 4 - 1)) << 2;
    float4 sc = *(const float4*)(scale + c4);
    float4 sh = *(const float4*)(shift + c4);
    float4 v = x[idx];
    bf16x4 o = { (bf16_t)fmaxf(fmaf(v.x, sc.x, sh.x), 0.f),
                 (bf16_t)fmaxf(fmaf(v.y, sc.y, sh.y), 0.f),
                 (bf16_t)fmaxf(fmaf(v.z, sc.z, sh.z), 0.f),
                 (bf16_t)fmaxf(fmaf(v.w, sc.w, sh.w), 0.f) };
    out[idx] = o;
}

// ---------------- head: out = log_softmax(z @ Wl2 + bl2) ----------------
__global__ __launch_bounds__(256)
void head_k(const float* __restrict__ z, const float* __restrict__ Wl2,
            const float* __restrict__ bl2, float* __restrict__ out)
{
    int wave = threadIdx.x >> 6;
    int lane = threadIdx.x & 63;
    int node = blockIdx.x * 4 + wave;              // grid = Nn/4 exact
    const float4 zv = *(const float4*)(z + (size_t)node * HMc + lane * 4);
    float p[DOUTc];
    #pragma unroll
    for (int j = 0; j < DOUTc; ++j) p[j] = 0.f;
    const float zz[4] = {zv.x, zv.y, zv.z, zv.w};
    #pragma unroll
    for (int i = 0; i < 4; ++i) {
        int k = lane * 4 + i;
        const float* wrow = Wl2 + (size_t)k * DOUTc;
        #pragma unroll
        for (int j = 0; j < DOUTc; ++j) p[j] = fmaf(zz[i], wrow[j], p[j]);
    }
    #pragma unroll
    for (int j = 0; j < DOUTc; ++j) {
        #pragma unroll
        for (int off = 32; off > 0; off >>= 1) p[j] += __shfl_down(p[j], off, 64);
    }
    if (lane == 0) {
        float v[DOUTc];
        float m = -1e30f;
        #pragma unroll
        for (int j = 0; j < DOUTc; ++j) { v[j] = p[j] + bl2[j]; m = fmaxf(m, v[j]); }
        float s = 0.f;
        #pragma unroll
        for (int j = 0; j < DOUTc; ++j) s += expf(v[j] - m);
        float ls = logf(s) + m;
        #pragma unroll
        for (int j = 0; j < DOUTc; ++j) out[(size_t)node * DOUTc + j] = v[j] - ls;
    }
}

// ---------------- launch ----------------
extern "C" void kernel_launch(void* const* d_in, const int* in_sizes, int n_in,
                              void* d_out, int out_size, void* d_ws, size_t ws_size,
                              hipStream_t stream)
{
    (void)in_sizes; (void)n_in; (void)out_size; (void)ws_size;
    const float* x    = (const float*)d_in[0];
    const int*   ei   = (const int*)d_in[1];
    const float* ew   = (const float*)d_in[2];
    const float* W1   = (const float*)d_in[3];
    // b1 = d_in[4]: cancels under batchnorm mean-subtraction
    const float* gam1 = (const float*)d_in[5];
    const float* bet1 = (const float*)d_in[6];
    const float* W2   = (const float*)d_in[7];
    // b2 = d_in[8]: cancels
    const float* gam2 = (const float*)d_in[9];
    const float* bet2 = (const float*)d_in[10];
    const float* Wl1  = (const float*)d_in[11];
    const float* bl1  = (const float*)d_in[12];
    const float* Wl2  = (const float*)d_in[13];
    const float* bl2  = (const float*)d_in[14];
    float* out = (float*)d_out;

    float* bufB  = (float*)d_ws;                   // Nn*Hc f32 (SpMM out)
    float* zhead = bufB + (size_t)Nn * Hc;         // Nn*HMc f32 (head GEMM out)
    float* dinv  = zhead + (size_t)Nn * HMc;       // Nn
    float* s1    = dinv + Nn;                      // Hc
    float* s2    = s1 + Hc;                        // Hc
    int*   cnt      = (int*)(s2 + Hc);             // Nn
    int*   row_ptr  = cnt + Nn;                    // Nn+16
    int*   cursor   = row_ptr + Nn + 16;           // Nn
    int*   csr_src  = cursor + Nn;                 // Ne
    float* csr_coef = (float*)(csr_src + Ne);      // Ne
    bf16_t* xb   = (bf16_t*)(csr_coef + Ne);       // Nn*DIN
    bf16_t* hgem = xb + (size_t)Nn * DIN;          // Nn*Hc  (GEMM1/2 bf16 out)
    bf16_t* hbf  = hgem + (size_t)Nn * Hc;         // Nn*Hc  (BN bf16 out)
    bf16_t* W1t  = hbf + (size_t)Nn * Hc;          // Hc*DIN  (= W1^T)
    bf16_t* W2t  = W1t + (size_t)Hc * DIN;         // Hc*Hc   (= W2^T)
    bf16_t* Wl1t = W2t + (size_t)Hc * Hc;          // HMc*Hc  (= Wl1^T)

    const int* srcv = ei;
    const int* dstv = ei + Ne;

    const int EW4 = Nn * Hc / 4 / 256;             // 20000 blocks for elementwise f4

    // ---- one-time per launch: dinv + CSR + bf16 weights/x ----
    deg_init_k<<<(Nn + 255) / 256, 256, 0, stream>>>(dinv, cnt);
    deg_edge_k<<<(Ne + 255) / 256, 256, 0, stream>>>(ew, dstv, dinv, cnt);
    dinv_k<<<(Nn + 255) / 256, 256, 0, stream>>>(dinv);
    scan_k<<<1, 1024, 0, stream>>>(cnt, row_ptr, cursor);
    csr_fill_k<<<(Ne + 255) / 256, 256, 0, stream>>>(srcv, dstv, ew, dinv, cursor,
                                                     csr_src, csr_coef);
    transpose_bf16_k<DIN, Hc><<<dim3(Hc / 32, DIN / 32), 256, 0, stream>>>(W1, W1t);
    transpose_bf16_k<Hc, Hc><<<dim3(Hc / 32, Hc / 32), 256, 0, stream>>>(W2, W2t);
    transpose_bf16_k<Hc, HMc><<<dim3(HMc / 32, Hc / 32), 256, 0, stream>>>(Wl1, Wl1t);
    cvt_bf16_k<<<(Nn * DIN / 4 + 255) / 256, 256, 0, stream>>>(
        (const float4*)x, (bf16x4*)xb, Nn * DIN / 4);

    const int MB = (Nn + 127) / 128;               // 157 row-blocks

    // layer 1
    gemm_bf16_k<Hc, DIN, false, false, true><<<dim3(Hc / 128, MB), 256, 0, stream>>>(
        xb, W1t, nullptr, hgem, Nn);
    spmm_bf16_k<<<Nn / 2, 256, 0, stream>>>((const bf16x8*)hgem, row_ptr, csr_src,
                                            csr_coef, dinv, (float4*)bufB);
    zero_stats_k<<<8, 256, 0, stream>>>(s1);
    bn_stats_k<<<dim3(Hc / 256, 80), 256, 0, stream>>>(bufB, s1, s2);
    bn_finalize_k<<<Hc / 256, 256, 0, stream>>>(s1, s2, gam1, bet1);
    bn_apply_k<<<EW4, 256, 0, stream>>>((const float4*)bufB, s1, s2, (bf16x4*)hbf);

    // layer 2
    gemm_bf16_k<Hc, Hc, false, false, true><<<dim3(Hc / 128, MB), 256, 0, stream>>>(
        hbf, W2t, nullptr, hgem, Nn);
    spmm_bf16_k<<<Nn / 2, 256, 0, stream>>>((const bf16x8*)hgem, row_ptr, csr_src,
                                            csr_coef, dinv, (float4*)bufB);
    zero_stats_k<<<8, 256, 0, stream>>>(s1);
    bn_stats_k<<<dim3(Hc / 256, 80), 256, 0, stream>>>(bufB, s1, s2);
    bn_finalize_k<<<Hc / 256, 256, 0, stream>>>(s1, s2, gam2, bet2);
    bn_apply_k<<<EW4, 256, 0, stream>>>((const float4*)bufB, s1, s2, (bf16x4*)hbf);

    // MLP head: z = relu(h @ Wl1 + bl1) (fp32 out), then fused GEMM+log_softmax
    gemm_bf16_k<HMc, Hc, true, true, false><<<dim3(HMc / 128, MB), 256, 0, stream>>>(
        hbf, Wl1t, bl1, zhead, Nn);
    head_k<<<Nn / 4, 256, 0, stream>>>(zhead, Wl2, bl2, out);
}

// Round 5
// 477.035 us; speedup vs baseline: 19.6496x; 1.2777x over previous
//
#include <hip/hip_runtime.h>
#include <math.h>

static constexpr int Nn  = 20000;
static constexpr int Ne  = 320000;
static constexpr int DIN = 128;
static constexpr int DOUTc = 10;
static constexpr int Hc  = 1024;
static constexpr int HMc = 256;
static constexpr float EPSc = 1e-5f;

typedef __bf16 bf16_t;
typedef __bf16 bf16x8 __attribute__((ext_vector_type(8)));
typedef __bf16 bf16x4 __attribute__((ext_vector_type(4)));
typedef float  f32x4  __attribute__((ext_vector_type(4)));

__device__ __forceinline__ void gload_lds16(const bf16_t* g, bf16_t* lds) {
    __builtin_amdgcn_global_load_lds(
        (const __attribute__((address_space(1))) void*)g,
        (__attribute__((address_space(3))) void*)lds, 16, 0, 0);
}

// ---------------- degree / count init ----------------
__global__ __launch_bounds__(256) void deg_init_k(float* __restrict__ deg, int* __restrict__ cnt) {
    int i = blockIdx.x * 256 + threadIdx.x;
    if (i < Nn) { deg[i] = 1.0f; cnt[i] = 0; }     // self-loop weight 1
}

__global__ __launch_bounds__(256)
void deg_edge_k(const float* __restrict__ w, const int* __restrict__ dstv,
                float* __restrict__ deg, int* __restrict__ cnt) {
    int e = blockIdx.x * 256 + threadIdx.x;
    if (e < Ne) {
        int d = dstv[e];
        atomicAdd(&deg[d], w[e]);
        atomicAdd(&cnt[d], 1);
    }
}

__global__ __launch_bounds__(256) void dinv_k(float* __restrict__ deg) {
    int i = blockIdx.x * 256 + threadIdx.x;
    if (i < Nn) deg[i] = rsqrtf(deg[i]);  // deg >= 1 always
}

// ---------------- single-block scan (wave-shuffle based) ----------------
__global__ __launch_bounds__(1024)
void scan_k(const int* __restrict__ cnt, int* __restrict__ row_ptr, int* __restrict__ cursor)
{
    __shared__ int wsum[16];
    __shared__ int tot_s;
    __shared__ int carry_s;
    const int tid  = threadIdx.x;
    const int lane = tid & 63;
    const int wv   = tid >> 6;
    if (tid == 0) carry_s = 0;
    __syncthreads();
    for (int base = 0; base < Nn; base += 1024) {
        int i = base + tid;
        int v = (i < Nn) ? cnt[i] : 0;
        int s = v;
        #pragma unroll
        for (int off = 1; off < 64; off <<= 1) {
            int t = __shfl_up(s, off, 64);
            if (lane >= off) s += t;
        }
        if (lane == 63) wsum[wv] = s;
        __syncthreads();
        if (tid < 16) {
            int t = wsum[tid];
            int s2v = t;
            #pragma unroll
            for (int off = 1; off < 16; off <<= 1) {
                int u = __shfl_up(s2v, off, 64);
                if (tid >= off) s2v += u;
            }
            wsum[tid] = s2v - t;               // exclusive prefix of wave sums
            if (tid == 15) tot_s = s2v;        // chunk total
        }
        __syncthreads();
        int carry = carry_s;
        if (i < Nn) {
            int excl = carry + wsum[wv] + s - v;
            row_ptr[i] = excl;
            cursor[i]  = excl;
        }
        __syncthreads();
        if (tid == 0) carry_s = carry + tot_s;
        __syncthreads();
    }
    if (tid == 0) row_ptr[Nn] = Ne;
}

// ---------------- CSR fill (coeff precomputed) ----------------
__global__ __launch_bounds__(256)
void csr_fill_k(const int* __restrict__ srcv, const int* __restrict__ dstv,
                const float* __restrict__ w, const float* __restrict__ dinv,
                int* __restrict__ cursor, int* __restrict__ csr_src,
                float* __restrict__ csr_coeff)
{
    int e = blockIdx.x * 256 + threadIdx.x;
    if (e >= Ne) return;
    int s = srcv[e], d = dstv[e];
    int pos = atomicAdd(&cursor[d], 1);
    csr_src[pos]   = s;
    csr_coeff[pos] = dinv[s] * w[e] * dinv[d];
}

// ---------------- gather SpMM over x (128-dim): 16 nodes/block, 16 lanes/node ----------------
__global__ __launch_bounds__(256)
void spmm_x_k(const bf16x8* __restrict__ x8, const int* __restrict__ row_ptr,
              const int* __restrict__ csr_src, const float* __restrict__ csr_coeff,
              const float* __restrict__ dinv, bf16x8* __restrict__ out8)
{
    int d = blockIdx.x * 16 + (threadIdx.x >> 4);  // grid = Nn/16 = 1250
    int f = threadIdx.x & 15;                      // DIN/8 == 16
    float c = dinv[d]; c = c * c;
    bf16x8 hv = x8[(size_t)d * 16 + f];
    float acc[8];
    #pragma unroll
    for (int i = 0; i < 8; ++i) acc[i] = c * (float)hv[i];
    int beg = row_ptr[d], end = row_ptr[d + 1];
    for (int j = beg; j < end; ++j) {
        int   s  = csr_src[j];
        float cf = csr_coeff[j];
        bf16x8 v = x8[(size_t)s * 16 + f];
        #pragma unroll
        for (int i = 0; i < 8; ++i) acc[i] = fmaf(cf, (float)v[i], acc[i]);
    }
    bf16x8 o;
    #pragma unroll
    for (int i = 0; i < 8; ++i) o[i] = (bf16_t)acc[i];
    out8[(size_t)d * 16 + f] = o;
}

// ---------------- gather SpMM over h (1024-dim, bf16 in/out): 2 nodes/block ----------------
__global__ __launch_bounds__(256)
void spmm_h_k(const bf16x8* __restrict__ h8, const int* __restrict__ row_ptr,
              const int* __restrict__ csr_src, const float* __restrict__ csr_coeff,
              const float* __restrict__ dinv, bf16x8* __restrict__ out8)
{
    int d = blockIdx.x * 2 + (threadIdx.x >> 7);
    int f = threadIdx.x & 127;                     // Hc/8 == 128
    float c = dinv[d]; c = c * c;
    bf16x8 hv = h8[(size_t)d * 128 + f];
    float acc[8];
    #pragma unroll
    for (int i = 0; i < 8; ++i) acc[i] = c * (float)hv[i];
    int beg = row_ptr[d], end = row_ptr[d + 1];
    for (int j = beg; j < end; ++j) {
        int   s  = csr_src[j];
        float cf = csr_coeff[j];
        bf16x8 v = h8[(size_t)s * 128 + f];
        #pragma unroll
        for (int i = 0; i < 8; ++i) acc[i] = fmaf(cf, (float)v[i], acc[i]);
    }
    bf16x8 o;
    #pragma unroll
    for (int i = 0; i < 8; ++i) o[i] = (bf16_t)acc[i];
    out8[(size_t)d * 128 + f] = o;
}

// ---------------- weight transpose + convert: Wt[n][k] = bf16(W[k][n]) ----------------
template<int RK, int CN>   // W is RK x CN fp32; Wt is CN x RK bf16
__global__ __launch_bounds__(256)
void transpose_bf16_k(const float* __restrict__ W, bf16_t* __restrict__ Wt)
{
    __shared__ float tile[32][33];
    int bx = blockIdx.x * 32;  // input col base
    int by = blockIdx.y * 32;  // input row base
    int tx = threadIdx.x & 31, ty = threadIdx.x >> 5;  // ty 0..7
    #pragma unroll
    for (int p = 0; p < 32; p += 8)
        tile[ty + p][tx] = W[(size_t)(by + ty + p) * CN + bx + tx];
    __syncthreads();
    #pragma unroll
    for (int p = 0; p < 32; p += 8)
        Wt[(size_t)(bx + ty + p) * RK + by + tx] = (bf16_t)tile[tx][ty + p];
}

// ---------------- fp32 -> bf16 convert (x) ----------------
__global__ __launch_bounds__(256)
void cvt_bf16_k(const float4* __restrict__ in, bf16x4* __restrict__ out, int n4)
{
    int i = blockIdx.x * 256 + threadIdx.x;
    if (i >= n4) return;
    float4 v = in[i];
    bf16x4 o = { (bf16_t)v.x, (bf16_t)v.y, (bf16_t)v.z, (bf16_t)v.w };
    out[i] = o;
}

// ---------------- bf16 MFMA GEMM: C[M x NC] = A[M x KD] @ Bt[NC x KD]^T ----------------
// 128x128 tile, 4 waves in 2x2, each wave 64x64 via 4x4 of 16x16x32 MFMA.
// OUTBF: store bf16. STATS: accumulate column sum/sumsq into s1g/s2g (for fused BN).
template<int NC, int KD, bool BIAS, bool RELU, bool OUTBF, bool STATS>
__global__ __launch_bounds__(256)
void gemm_bf16_k(const bf16_t* __restrict__ A, const bf16_t* __restrict__ Bt,
                 const float* __restrict__ bias, void* __restrict__ Cv, int M,
                 float* __restrict__ s1g, float* __restrict__ s2g)
{
    __shared__ __align__(16) bf16_t Asm[128 * 32];
    __shared__ __align__(16) bf16_t Bsm[128 * 32];
    const int tid  = threadIdx.x;
    const int w    = tid >> 6;
    const int lane = tid & 63;
    const int bm = blockIdx.y * 128, bn = blockIdx.x * 128;
    const int l15 = lane & 15, quad = lane >> 4;
    const int wm = (w & 1) * 64, wn = (w >> 1) * 64;
    const int swz = quad ^ ((l15 >> 1) & 3);

    // staging: wave w owns tile rows [w*32, w*32+32), two 16-row chunks
    const int srow = lane >> 2;                              // row within chunk
    const int scol = 8 * ((lane & 3) ^ ((lane >> 3) & 3));   // k offset within 32
    const int c0 = w * 32;
    int ga0 = bm + c0 + srow;       if (ga0 >= M) ga0 = M - 1;
    int ga1 = bm + c0 + 16 + srow;  if (ga1 >= M) ga1 = M - 1;
    const bf16_t* gA0 = A + (size_t)ga0 * KD + scol;
    const bf16_t* gA1 = A + (size_t)ga1 * KD + scol;
    const bf16_t* gB0 = Bt + (size_t)(bn + c0 + srow) * KD + scol;
    const bf16_t* gB1 = gB0 + (size_t)16 * KD;
    bf16_t* lA0 = Asm + (c0 +  0) * 32;
    bf16_t* lA1 = Asm + (c0 + 16) * 32;
    bf16_t* lB0 = Bsm + (c0 +  0) * 32;
    bf16_t* lB1 = Bsm + (c0 + 16) * 32;

    // fragment read bases
    const bf16_t* pA = Asm + (wm + l15) * 32 + swz * 8;
    const bf16_t* pB = Bsm + (wn + l15) * 32 + swz * 8;

    f32x4 acc[4][4] = {};

    for (int k0 = 0; k0 < KD; k0 += 32) {
        gload_lds16(gA0 + k0, lA0);
        gload_lds16(gA1 + k0, lA1);
        gload_lds16(gB0 + k0, lB0);
        gload_lds16(gB1 + k0, lB1);
        __syncthreads();
        bf16x8 af[4], bfr[4];
        #pragma unroll
        for (int t = 0; t < 4; ++t) {
            af[t]  = *(const bf16x8*)(pA + t * 16 * 32);
            bfr[t] = *(const bf16x8*)(pB + t * 16 * 32);
        }
        #pragma unroll
        for (int mt = 0; mt < 4; ++mt)
            #pragma unroll
            for (int nt = 0; nt < 4; ++nt)
                acc[mt][nt] = __builtin_amdgcn_mfma_f32_16x16x32_bf16(
                    af[mt], bfr[nt], acc[mt][nt], 0, 0, 0);
        __syncthreads();
    }

    // epilogue: D row = quad*4 + r, col = l15 within each 16x16 tile
    #pragma unroll
    for (int mt = 0; mt < 4; ++mt) {
        #pragma unroll
        for (int r = 0; r < 4; ++r) {
            int row = bm + wm + mt * 16 + quad * 4 + r;
            if (row >= M) continue;
            #pragma unroll
            for (int nt = 0; nt < 4; ++nt) {
                int col = bn + wn + nt * 16 + l15;
                float v = acc[mt][nt][r];
                if (BIAS) v += bias[col];
                if (RELU) v = fmaxf(v, 0.f);
                if (OUTBF) ((bf16_t*)Cv)[(size_t)row * NC + col] = (bf16_t)v;
                else       ((float*)Cv)[(size_t)row * NC + col] = v;
            }
        }
    }

    if (STATS) {
        #pragma unroll
        for (int nt = 0; nt < 4; ++nt) {
            float ps = 0.f, pq = 0.f;
            #pragma unroll
            for (int mt = 0; mt < 4; ++mt)
                #pragma unroll
                for (int r = 0; r < 4; ++r) {
                    int row = bm + wm + mt * 16 + quad * 4 + r;
                    if (row < M) {
                        float v = acc[mt][nt][r];
                        ps += v;
                        pq = fmaf(v, v, pq);
                    }
                }
            ps += __shfl_down(ps, 32, 64); ps += __shfl_down(ps, 16, 64);
            pq += __shfl_down(pq, 32, 64); pq += __shfl_down(pq, 16, 64);
            if (quad == 0) {
                int col = bn + wn + nt * 16 + l15;
                atomicAdd(&s1g[col], ps);
                atomicAdd(&s2g[col], pq);
            }
        }
    }
}

// ---------------- batchnorm ----------------
__global__ __launch_bounds__(256) void zero_stats_k(float* __restrict__ s) {
    int i = blockIdx.x * 256 + threadIdx.x;        // grid 8 -> 2048 = 2*Hc
    s[i] = 0.f;
}

// column stats over bf16 matrix
__global__ __launch_bounds__(256)
void bn_stats_k(const bf16_t* __restrict__ x, float* __restrict__ s1, float* __restrict__ s2)
{
    int c = blockIdx.x * 256 + threadIdx.x;        // < Hc (grid.x = 4)
    int r0 = blockIdx.y * 250;                     // 80 chunks * 250 = 20000
    float s = 0.f, q = 0.f;
    const bf16_t* p = x + (size_t)r0 * Hc + c;
    for (int r = 0; r < 250; ++r) {
        float v = (float)p[(size_t)r * Hc];
        s += v;
        q = fmaf(v, v, q);
    }
    atomicAdd(&s1[c], s);
    atomicAdd(&s2[c], q);
}

// fused finalize+apply: reads raw sums, computes scale/shift inline, BN+ReLU, bf16->bf16
__global__ __launch_bounds__(256)
void bn_apply_k(const bf16x8* __restrict__ x8, const float* __restrict__ s1,
                const float* __restrict__ s2, const float* __restrict__ g,
                const float* __restrict__ beta, bf16x8* __restrict__ out8)
{
    int idx = blockIdx.x * 256 + threadIdx.x;      // grid = Nn*Hc/8/256 = 10000
    int c8 = (idx & 127) << 3;
    bf16x8 v = x8[idx];
    bf16x8 o;
    #pragma unroll
    for (int i = 0; i < 8; ++i) {
        int c = c8 + i;
        float mean = s1[c] * (1.0f / Nn);
        float var  = s2[c] * (1.0f / Nn) - mean * mean;
        float sc = g[c] * rsqrtf(var + EPSc);
        float sh = beta[c] - mean * sc;
        o[i] = (bf16_t)fmaxf(fmaf((float)v[i], sc, sh), 0.f);
    }
    out8[idx] = o;
}

// ---------------- head: out = log_softmax(z @ Wl2 + bl2) ----------------
__global__ __launch_bounds__(256)
void head_k(const float* __restrict__ z, const float* __restrict__ Wl2,
            const float* __restrict__ bl2, float* __restrict__ out)
{
    int wave = threadIdx.x >> 6;
    int lane = threadIdx.x & 63;
    int node = blockIdx.x * 4 + wave;              // grid = Nn/4 exact
    const float4 zv = *(const float4*)(z + (size_t)node * HMc + lane * 4);
    float p[DOUTc];
    #pragma unroll
    for (int j = 0; j < DOUTc; ++j) p[j] = 0.f;
    const float zz[4] = {zv.x, zv.y, zv.z, zv.w};
    #pragma unroll
    for (int i = 0; i < 4; ++i) {
        int k = lane * 4 + i;
        const float* wrow = Wl2 + (size_t)k * DOUTc;
        #pragma unroll
        for (int j = 0; j < DOUTc; ++j) p[j] = fmaf(zz[i], wrow[j], p[j]);
    }
    #pragma unroll
    for (int j = 0; j < DOUTc; ++j) {
        #pragma unroll
        for (int off = 32; off > 0; off >>= 1) p[j] += __shfl_down(p[j], off, 64);
    }
    if (lane == 0) {
        float v[DOUTc];
        float m = -1e30f;
        #pragma unroll
        for (int j = 0; j < DOUTc; ++j) { v[j] = p[j] + bl2[j]; m = fmaxf(m, v[j]); }
        float s = 0.f;
        #pragma unroll
        for (int j = 0; j < DOUTc; ++j) s += expf(v[j] - m);
        float ls = logf(s) + m;
        #pragma unroll
        for (int j = 0; j < DOUTc; ++j) out[(size_t)node * DOUTc + j] = v[j] - ls;
    }
}

// ---------------- launch ----------------
extern "C" void kernel_launch(void* const* d_in, const int* in_sizes, int n_in,
                              void* d_out, int out_size, void* d_ws, size_t ws_size,
                              hipStream_t stream)
{
    (void)in_sizes; (void)n_in; (void)out_size; (void)ws_size;
    const float* x    = (const float*)d_in[0];
    const int*   ei   = (const int*)d_in[1];
    const float* ew   = (const float*)d_in[2];
    const float* W1   = (const float*)d_in[3];
    // b1 = d_in[4]: cancels under batchnorm mean-subtraction
    const float* gam1 = (const float*)d_in[5];
    const float* bet1 = (const float*)d_in[6];
    const float* W2   = (const float*)d_in[7];
    // b2 = d_in[8]: cancels
    const float* gam2 = (const float*)d_in[9];
    const float* bet2 = (const float*)d_in[10];
    const float* Wl1  = (const float*)d_in[11];
    const float* bl1  = (const float*)d_in[12];
    const float* Wl2  = (const float*)d_in[13];
    const float* bl2  = (const float*)d_in[14];
    float* out = (float*)d_out;

    float* zhead = (float*)d_ws;                   // Nn*HMc f32 (head GEMM out)
    float* dinv  = zhead + (size_t)Nn * HMc;       // Nn
    float* s1    = dinv + Nn;                      // Hc
    float* s2    = s1 + Hc;                        // Hc
    int*   cnt      = (int*)(s2 + Hc);             // Nn
    int*   row_ptr  = cnt + Nn;                    // Nn+16
    int*   cursor   = row_ptr + Nn + 16;           // Nn
    int*   csr_src  = cursor + Nn;                 // Ne
    float* csr_coef = (float*)(csr_src + Ne);      // Ne
    bf16_t* xb   = (bf16_t*)(csr_coef + Ne);       // Nn*DIN  (16B aligned)
    bf16_t* xagg = xb + (size_t)Nn * DIN;          // Nn*DIN  (aggregated x)
    bf16_t* hgem = xagg + (size_t)Nn * DIN;        // Nn*Hc   ping
    bf16_t* hbf  = hgem + (size_t)Nn * Hc;         // Nn*Hc   pong
    bf16_t* W1t  = hbf + (size_t)Nn * Hc;          // Hc*DIN  (= W1^T)
    bf16_t* W2t  = W1t + (size_t)Hc * DIN;         // Hc*Hc   (= W2^T)
    bf16_t* Wl1t = W2t + (size_t)Hc * Hc;          // HMc*Hc  (= Wl1^T)

    const int* srcv = ei;
    const int* dstv = ei + Ne;

    // ---- one-time per launch: dinv + CSR + bf16 weights/x ----
    deg_init_k<<<(Nn + 255) / 256, 256, 0, stream>>>(dinv, cnt);
    deg_edge_k<<<(Ne + 255) / 256, 256, 0, stream>>>(ew, dstv, dinv, cnt);
    dinv_k<<<(Nn + 255) / 256, 256, 0, stream>>>(dinv);
    scan_k<<<1, 1024, 0, stream>>>(cnt, row_ptr, cursor);
    csr_fill_k<<<(Ne + 255) / 256, 256, 0, stream>>>(srcv, dstv, ew, dinv, cursor,
                                                     csr_src, csr_coef);
    transpose_bf16_k<DIN, Hc><<<dim3(Hc / 32, DIN / 32), 256, 0, stream>>>(W1, W1t);
    transpose_bf16_k<Hc, Hc><<<dim3(Hc / 32, Hc / 32), 256, 0, stream>>>(W2, W2t);
    transpose_bf16_k<Hc, HMc><<<dim3(HMc / 32, Hc / 32), 256, 0, stream>>>(Wl1, Wl1t);
    cvt_bf16_k<<<(Nn * DIN / 4 + 255) / 256, 256, 0, stream>>>(
        (const float4*)x, (bf16x4*)xb, Nn * DIN / 4);

    const int MB = (Nn + 127) / 128;               // 157 row-blocks

    // layer 1:  (A X) W1  — aggregate first (128-dim), then GEMM with fused BN stats
    spmm_x_k<<<Nn / 16, 256, 0, stream>>>((const bf16x8*)xb, row_ptr, csr_src,
                                          csr_coef, dinv, (bf16x8*)xagg);
    zero_stats_k<<<8, 256, 0, stream>>>(s1);
    gemm_bf16_k<Hc, DIN, false, false, true, true><<<dim3(Hc / 128, MB), 256, 0, stream>>>(
        xagg, W1t, nullptr, hgem, Nn, s1, s2);
    bn_apply_k<<<Nn * Hc / 8 / 256, 256, 0, stream>>>(
        (const bf16x8*)hgem, s1, s2, gam1, bet1, (bf16x8*)hbf);

    // layer 2:  GEMM, aggregate (1024-dim), BN
    gemm_bf16_k<Hc, Hc, false, false, true, false><<<dim3(Hc / 128, MB), 256, 0, stream>>>(
        hbf, W2t, nullptr, hgem, Nn, nullptr, nullptr);
    spmm_h_k<<<Nn / 2, 256, 0, stream>>>((const bf16x8*)hgem, row_ptr, csr_src,
                                         csr_coef, dinv, (bf16x8*)hbf);
    zero_stats_k<<<8, 256, 0, stream>>>(s1);
    bn_stats_k<<<dim3(Hc / 256, 80), 256, 0, stream>>>(hbf, s1, s2);
    bn_apply_k<<<Nn * Hc / 8 / 256, 256, 0, stream>>>(
        (const bf16x8*)hbf, s1, s2, gam2, bet2, (bf16x8*)hgem);

    // MLP head: z = relu(h @ Wl1 + bl1) (fp32 out), then fused GEMM+log_softmax
    gemm_bf16_k<HMc, Hc, true, true, false, false><<<dim3(HMc / 128, MB), 256, 0, stream>>>(
        hgem, Wl1t, bl1, zhead, Nn, nullptr, nullptr);
    head_k<<<Nn / 4, 256, 0, stream>>>(zhead, Wl2, bl2, out);
}

// Round 6
// 461.879 us; speedup vs baseline: 20.2944x; 1.0328x over previous
//
#include <hip/hip_runtime.h>
#include <math.h>

static constexpr int Nn  = 20000;
static constexpr int Ne  = 320000;
static constexpr int DIN = 128;
static constexpr int DOUTc = 10;
static constexpr int Hc  = 1024;
static constexpr int HMc = 256;
static constexpr float EPSc = 1e-5f;
static constexpr int NB_SCAN = (Nn + 255) / 256;   // 79

typedef __bf16 bf16_t;
typedef __bf16 bf16x8 __attribute__((ext_vector_type(8)));
typedef __bf16 bf16x4 __attribute__((ext_vector_type(4)));
typedef float  f32x4  __attribute__((ext_vector_type(4)));

__device__ __forceinline__ void gload_lds16(const bf16_t* g, bf16_t* lds) {
    __builtin_amdgcn_global_load_lds(
        (const __attribute__((address_space(1))) void*)g,
        (__attribute__((address_space(3))) void*)lds, 16, 0, 0);
}

// ---------------- degree / count init ----------------
__global__ __launch_bounds__(256) void deg_init_k(float* __restrict__ deg, int* __restrict__ cnt) {
    int i = blockIdx.x * 256 + threadIdx.x;
    if (i < Nn) { deg[i] = 1.0f; cnt[i] = 0; }     // self-loop weight 1
}

__global__ __launch_bounds__(256)
void deg_edge_k(const float* __restrict__ w, const int* __restrict__ dstv,
                float* __restrict__ deg, int* __restrict__ cnt) {
    int e = blockIdx.x * 256 + threadIdx.x;
    if (e < Ne) {
        int d = dstv[e];
        atomicAdd(&deg[d], w[e]);
        atomicAdd(&cnt[d], 1);
    }
}

__global__ __launch_bounds__(256) void dinv_k(float* __restrict__ deg) {
    int i = blockIdx.x * 256 + threadIdx.x;
    if (i < Nn) deg[i] = rsqrtf(deg[i]);  // deg >= 1 always
}

// ---------------- 3-kernel block scan: cnt -> row_ptr/cursor ----------------
__global__ __launch_bounds__(256)
void scanA_k(const int* __restrict__ cnt, int* __restrict__ row_ptr, int* __restrict__ blk)
{
    __shared__ int wsum[4];
    int b = blockIdx.x, tid = threadIdx.x, lane = tid & 63, wv = tid >> 6;
    int i = b * 256 + tid;
    int v = (i < Nn) ? cnt[i] : 0;
    int s = v;
    #pragma unroll
    for (int off = 1; off < 64; off <<= 1) {
        int t = __shfl_up(s, off, 64);
        if (lane >= off) s += t;
    }
    if (lane == 63) wsum[wv] = s;
    __syncthreads();
    int wo = 0;
    #pragma unroll
    for (int k = 0; k < 4; ++k) if (k < wv) wo += wsum[k];
    if (i < Nn) row_ptr[i] = wo + s - v;           // block-local exclusive
    if (tid == 255) blk[b] = wo + s;               // block total
}

__global__ __launch_bounds__(128)
void scanB_k(int* __restrict__ blk)                // NB_SCAN <= 128
{
    __shared__ int w0;
    int tid = threadIdx.x, lane = tid & 63, wv = tid >> 6;
    int v = (tid < NB_SCAN) ? blk[tid] : 0;
    int s = v;
    #pragma unroll
    for (int off = 1; off < 64; off <<= 1) {
        int t = __shfl_up(s, off, 64);
        if (lane >= off) s += t;
    }
    if (tid == 63) w0 = s;
    __syncthreads();
    int excl = s - v + (wv ? w0 : 0);
    if (tid < NB_SCAN) blk[tid] = excl;
}

__global__ __launch_bounds__(256)
void scanC_k(int* __restrict__ row_ptr, const int* __restrict__ blk, int* __restrict__ cursor)
{
    int b = blockIdx.x;
    int i = b * 256 + threadIdx.x;
    if (i < Nn) {
        int r = row_ptr[i] + blk[b];
        row_ptr[i] = r;
        cursor[i]  = r;
    }
    if (i == 0) row_ptr[Nn] = Ne;
}

// ---------------- CSR fill (coeff precomputed) ----------------
__global__ __launch_bounds__(256)
void csr_fill_k(const int* __restrict__ srcv, const int* __restrict__ dstv,
                const float* __restrict__ w, const float* __restrict__ dinv,
                int* __restrict__ cursor, int* __restrict__ csr_src,
                float* __restrict__ csr_coeff)
{
    int e = blockIdx.x * 256 + threadIdx.x;
    if (e >= Ne) return;
    int s = srcv[e], d = dstv[e];
    int pos = atomicAdd(&cursor[d], 1);
    csr_src[pos]   = s;
    csr_coeff[pos] = dinv[s] * w[e] * dinv[d];
}

// ---------------- gather SpMM over x (128-dim), XCD-panel partitioned ----------------
// 4 panels x 32 feats. panel = blockIdx&3 so XCD k (blockIdx%8) serves only panel k%4:
// per-XCD slab = 20000*64B = 1.3 MB -> L2-resident. 64 nodes/block, 4 lanes/node.
__global__ __launch_bounds__(256)
void spmm_x_k(const bf16x8* __restrict__ x8, const int* __restrict__ row_ptr,
              const int* __restrict__ csr_src, const float* __restrict__ csr_coeff,
              const float* __restrict__ dinv, bf16x8* __restrict__ out8)
{
    int panel = blockIdx.x & 3;
    int node  = (blockIdx.x >> 2) * 64 + (threadIdx.x >> 2);
    if (node >= Nn) return;
    int f = (threadIdx.x & 3) + panel * 4;         // bf16x8 units within 16-unit row
    float c = dinv[node]; c = c * c;
    bf16x8 hv = x8[(size_t)node * 16 + f];
    float acc[8];
    #pragma unroll
    for (int i = 0; i < 8; ++i) acc[i] = c * (float)hv[i];
    int beg = row_ptr[node], end = row_ptr[node + 1];
    for (int j = beg; j < end; ++j) {
        int   s  = csr_src[j];
        float cf = csr_coeff[j];
        bf16x8 v = x8[(size_t)s * 16 + f];
        #pragma unroll
        for (int i = 0; i < 8; ++i) acc[i] = fmaf(cf, (float)v[i], acc[i]);
    }
    bf16x8 o;
    #pragma unroll
    for (int i = 0; i < 8; ++i) o[i] = (bf16_t)acc[i];
    out8[(size_t)node * 16 + f] = o;
}

// ---------------- gather SpMM over h (1024-dim), XCD-panel partitioned ----------------
// 8 panels x 128 feats. panel = blockIdx&7 -> XCD k serves only panel k:
// per-XCD slab = 20000*256B = 5.1 MB vs 4 MB L2 (mostly resident). 16 nodes/block.
__global__ __launch_bounds__(256)
void spmm_h_k(const bf16x8* __restrict__ h8, const int* __restrict__ row_ptr,
              const int* __restrict__ csr_src, const float* __restrict__ csr_coeff,
              const float* __restrict__ dinv, bf16x8* __restrict__ out8)
{
    int panel = blockIdx.x & 7;
    int node  = (blockIdx.x >> 3) * 16 + (threadIdx.x >> 4);   // grid = 8*1250 exact
    int f     = (threadIdx.x & 15) + panel * 16;   // bf16x8 units within 128-unit row
    float c = dinv[node]; c = c * c;
    bf16x8 hv = h8[(size_t)node * 128 + f];
    float acc[8];
    #pragma unroll
    for (int i = 0; i < 8; ++i) acc[i] = c * (float)hv[i];
    int beg = row_ptr[node], end = row_ptr[node + 1];
    for (int j = beg; j < end; ++j) {
        int   s  = csr_src[j];
        float cf = csr_coeff[j];
        bf16x8 v = h8[(size_t)s * 128 + f];
        #pragma unroll
        for (int i = 0; i < 8; ++i) acc[i] = fmaf(cf, (float)v[i], acc[i]);
    }
    bf16x8 o;
    #pragma unroll
    for (int i = 0; i < 8; ++i) o[i] = (bf16_t)acc[i];
    out8[(size_t)node * 128 + f] = o;
}

// ---------------- weight transpose + convert: Wt[n][k] = bf16(W[k][n]) ----------------
template<int RK, int CN>   // W is RK x CN fp32; Wt is CN x RK bf16
__global__ __launch_bounds__(256)
void transpose_bf16_k(const float* __restrict__ W, bf16_t* __restrict__ Wt)
{
    __shared__ float tile[32][33];
    int bx = blockIdx.x * 32;  // input col base
    int by = blockIdx.y * 32;  // input row base
    int tx = threadIdx.x & 31, ty = threadIdx.x >> 5;  // ty 0..7
    #pragma unroll
    for (int p = 0; p < 32; p += 8)
        tile[ty + p][tx] = W[(size_t)(by + ty + p) * CN + bx + tx];
    __syncthreads();
    #pragma unroll
    for (int p = 0; p < 32; p += 8)
        Wt[(size_t)(bx + ty + p) * RK + by + tx] = (bf16_t)tile[tx][ty + p];
}

// ---------------- fp32 -> bf16 convert (x) ----------------
__global__ __launch_bounds__(256)
void cvt_bf16_k(const float4* __restrict__ in, bf16x4* __restrict__ out, int n4)
{
    int i = blockIdx.x * 256 + threadIdx.x;
    if (i >= n4) return;
    float4 v = in[i];
    bf16x4 o = { (bf16_t)v.x, (bf16_t)v.y, (bf16_t)v.z, (bf16_t)v.w };
    out[i] = o;
}

// ---------------- bf16 MFMA GEMM: C[M x NC] = A[M x KD] @ Bt[NC x KD]^T ----------------
// 128x128 tile, 4 waves in 2x2, each wave 64x64 via 4x4 of 16x16x32 MFMA.
// OUTBF: store bf16. STATS: accumulate column sum/sumsq into s1g/s2g (for fused BN).
template<int NC, int KD, bool BIAS, bool RELU, bool OUTBF, bool STATS>
__global__ __launch_bounds__(256)
void gemm_bf16_k(const bf16_t* __restrict__ A, const bf16_t* __restrict__ Bt,
                 const float* __restrict__ bias, void* __restrict__ Cv, int M,
                 float* __restrict__ s1g, float* __restrict__ s2g)
{
    __shared__ __align__(16) bf16_t Asm[128 * 32];
    __shared__ __align__(16) bf16_t Bsm[128 * 32];
    const int tid  = threadIdx.x;
    const int w    = tid >> 6;
    const int lane = tid & 63;
    const int bm = blockIdx.y * 128, bn = blockIdx.x * 128;
    const int l15 = lane & 15, quad = lane >> 4;
    const int wm = (w & 1) * 64, wn = (w >> 1) * 64;
    const int swz = quad ^ ((l15 >> 1) & 3);

    // staging: wave w owns tile rows [w*32, w*32+32), two 16-row chunks
    const int srow = lane >> 2;                              // row within chunk
    const int scol = 8 * ((lane & 3) ^ ((lane >> 3) & 3));   // k offset within 32
    const int c0 = w * 32;
    int ga0 = bm + c0 + srow;       if (ga0 >= M) ga0 = M - 1;
    int ga1 = bm + c0 + 16 + srow;  if (ga1 >= M) ga1 = M - 1;
    const bf16_t* gA0 = A + (size_t)ga0 * KD + scol;
    const bf16_t* gA1 = A + (size_t)ga1 * KD + scol;
    const bf16_t* gB0 = Bt + (size_t)(bn + c0 + srow) * KD + scol;
    const bf16_t* gB1 = gB0 + (size_t)16 * KD;
    bf16_t* lA0 = Asm + (c0 +  0) * 32;
    bf16_t* lA1 = Asm + (c0 + 16) * 32;
    bf16_t* lB0 = Bsm + (c0 +  0) * 32;
    bf16_t* lB1 = Bsm + (c0 + 16) * 32;

    // fragment read bases
    const bf16_t* pA = Asm + (wm + l15) * 32 + swz * 8;
    const bf16_t* pB = Bsm + (wn + l15) * 32 + swz * 8;

    f32x4 acc[4][4] = {};

    for (int k0 = 0; k0 < KD; k0 += 32) {
        gload_lds16(gA0 + k0, lA0);
        gload_lds16(gA1 + k0, lA1);
        gload_lds16(gB0 + k0, lB0);
        gload_lds16(gB1 + k0, lB1);
        __syncthreads();
        bf16x8 af[4], bfr[4];
        #pragma unroll
        for (int t = 0; t < 4; ++t) {
            af[t]  = *(const bf16x8*)(pA + t * 16 * 32);
            bfr[t] = *(const bf16x8*)(pB + t * 16 * 32);
        }
        #pragma unroll
        for (int mt = 0; mt < 4; ++mt)
            #pragma unroll
            for (int nt = 0; nt < 4; ++nt)
                acc[mt][nt] = __builtin_amdgcn_mfma_f32_16x16x32_bf16(
                    af[mt], bfr[nt], acc[mt][nt], 0, 0, 0);
        __syncthreads();
    }

    // epilogue: D row = quad*4 + r, col = l15 within each 16x16 tile
    #pragma unroll
    for (int mt = 0; mt < 4; ++mt) {
        #pragma unroll
        for (int r = 0; r < 4; ++r) {
            int row = bm + wm + mt * 16 + quad * 4 + r;
            if (row >= M) continue;
            #pragma unroll
            for (int nt = 0; nt < 4; ++nt) {
                int col = bn + wn + nt * 16 + l15;
                float v = acc[mt][nt][r];
                if (BIAS) v += bias[col];
                if (RELU) v = fmaxf(v, 0.f);
                if (OUTBF) ((bf16_t*)Cv)[(size_t)row * NC + col] = (bf16_t)v;
                else       ((float*)Cv)[(size_t)row * NC + col] = v;
            }
        }
    }

    if (STATS) {
        #pragma unroll
        for (int nt = 0; nt < 4; ++nt) {
            float ps = 0.f, pq = 0.f;
            #pragma unroll
            for (int mt = 0; mt < 4; ++mt)
                #pragma unroll
                for (int r = 0; r < 4; ++r) {
                    int row = bm + wm + mt * 16 + quad * 4 + r;
                    if (row < M) {
                        float v = acc[mt][nt][r];
                        ps += v;
                        pq = fmaf(v, v, pq);
                    }
                }
            ps += __shfl_down(ps, 32, 64); ps += __shfl_down(ps, 16, 64);
            pq += __shfl_down(pq, 32, 64); pq += __shfl_down(pq, 16, 64);
            if (quad == 0) {
                int col = bn + wn + nt * 16 + l15;
                atomicAdd(&s1g[col], ps);
                atomicAdd(&s2g[col], pq);
            }
        }
    }
}

// ---------------- batchnorm ----------------
__global__ __launch_bounds__(256) void zero_stats_k(float* __restrict__ s) {
    int i = blockIdx.x * 256 + threadIdx.x;        // grid 8 -> 2048 = 2*Hc
    s[i] = 0.f;
}

// column stats over bf16 matrix
__global__ __launch_bounds__(256)
void bn_stats_k(const bf16_t* __restrict__ x, float* __restrict__ s1, float* __restrict__ s2)
{
    int c = blockIdx.x * 256 + threadIdx.x;        // < Hc (grid.x = 4)
    int r0 = blockIdx.y * 250;                     // 80 chunks * 250 = 20000
    float s = 0.f, q = 0.f;
    const bf16_t* p = x + (size_t)r0 * Hc + c;
    for (int r = 0; r < 250; ++r) {
        float v = (float)p[(size_t)r * Hc];
        s += v;
        q = fmaf(v, v, q);
    }
    atomicAdd(&s1[c], s);
    atomicAdd(&s2[c], q);
}

// fused finalize+apply: reads raw sums, computes scale/shift inline, BN+ReLU, bf16->bf16
__global__ __launch_bounds__(256)
void bn_apply_k(const bf16x8* __restrict__ x8, const float* __restrict__ s1,
                const float* __restrict__ s2, const float* __restrict__ g,
                const float* __restrict__ beta, bf16x8* __restrict__ out8)
{
    int idx = blockIdx.x * 256 + threadIdx.x;      // grid = Nn*Hc/8/256 = 10000
    int c8 = (idx & 127) << 3;
    bf16x8 v = x8[idx];
    bf16x8 o;
    #pragma unroll
    for (int i = 0; i < 8; ++i) {
        int c = c8 + i;
        float mean = s1[c] * (1.0f / Nn);
        float var  = s2[c] * (1.0f / Nn) - mean * mean;
        float sc = g[c] * rsqrtf(var + EPSc);
        float sh = beta[c] - mean * sc;
        o[i] = (bf16_t)fmaxf(fmaf((float)v[i], sc, sh), 0.f);
    }
    out8[idx] = o;
}

// ---------------- head: out = log_softmax(z @ Wl2 + bl2) ----------------
__global__ __launch_bounds__(256)
void head_k(const float* __restrict__ z, const float* __restrict__ Wl2,
            const float* __restrict__ bl2, float* __restrict__ out)
{
    int wave = threadIdx.x >> 6;
    int lane = threadIdx.x & 63;
    int node = blockIdx.x * 4 + wave;              // grid = Nn/4 exact
    const float4 zv = *(const float4*)(z + (size_t)node * HMc + lane * 4);
    float p[DOUTc];
    #pragma unroll
    for (int j = 0; j < DOUTc; ++j) p[j] = 0.f;
    const float zz[4] = {zv.x, zv.y, zv.z, zv.w};
    #pragma unroll
    for (int i = 0; i < 4; ++i) {
        int k = lane * 4 + i;
        const float* wrow = Wl2 + (size_t)k * DOUTc;
        #pragma unroll
        for (int j = 0; j < DOUTc; ++j) p[j] = fmaf(zz[i], wrow[j], p[j]);
    }
    #pragma unroll
    for (int j = 0; j < DOUTc; ++j) {
        #pragma unroll
        for (int off = 32; off > 0; off >>= 1) p[j] += __shfl_down(p[j], off, 64);
    }
    if (lane == 0) {
        float v[DOUTc];
        float m = -1e30f;
        #pragma unroll
        for (int j = 0; j < DOUTc; ++j) { v[j] = p[j] + bl2[j]; m = fmaxf(m, v[j]); }
        float s = 0.f;
        #pragma unroll
        for (int j = 0; j < DOUTc; ++j) s += expf(v[j] - m);
        float ls = logf(s) + m;
        #pragma unroll
        for (int j = 0; j < DOUTc; ++j) out[(size_t)node * DOUTc + j] = v[j] - ls;
    }
}

// ---------------- launch ----------------
extern "C" void kernel_launch(void* const* d_in, const int* in_sizes, int n_in,
                              void* d_out, int out_size, void* d_ws, size_t ws_size,
                              hipStream_t stream)
{
    (void)in_sizes; (void)n_in; (void)out_size; (void)ws_size;
    const float* x    = (const float*)d_in[0];
    const int*   ei   = (const int*)d_in[1];
    const float* ew   = (const float*)d_in[2];
    const float* W1   = (const float*)d_in[3];
    // b1 = d_in[4]: cancels under batchnorm mean-subtraction
    const float* gam1 = (const float*)d_in[5];
    const float* bet1 = (const float*)d_in[6];
    const float* W2   = (const float*)d_in[7];
    // b2 = d_in[8]: cancels
    const float* gam2 = (const float*)d_in[9];
    const float* bet2 = (const float*)d_in[10];
    const float* Wl1  = (const float*)d_in[11];
    const float* bl1  = (const float*)d_in[12];
    const float* Wl2  = (const float*)d_in[13];
    const float* bl2  = (const float*)d_in[14];
    float* out = (float*)d_out;

    float* zhead = (float*)d_ws;                   // Nn*HMc f32 (head GEMM out)
    float* dinv  = zhead + (size_t)Nn * HMc;       // Nn
    float* s1    = dinv + Nn;                      // Hc
    float* s2    = s1 + Hc;                        // Hc
    int*   cnt      = (int*)(s2 + Hc);             // Nn
    int*   row_ptr  = cnt + Nn;                    // Nn+16
    int*   cursor   = row_ptr + Nn + 16;           // Nn
    int*   blk      = cursor + Nn;                 // NB_SCAN (+pad)
    int*   csr_src  = blk + 128;                   // Ne
    float* csr_coef = (float*)(csr_src + Ne);      // Ne
    bf16_t* xb   = (bf16_t*)(csr_coef + Ne);       // Nn*DIN  (16B aligned)
    bf16_t* xagg = xb + (size_t)Nn * DIN;          // Nn*DIN  (aggregated x)
    bf16_t* hgem = xagg + (size_t)Nn * DIN;        // Nn*Hc   ping
    bf16_t* hbf  = hgem + (size_t)Nn * Hc;         // Nn*Hc   pong
    bf16_t* W1t  = hbf + (size_t)Nn * Hc;          // Hc*DIN  (= W1^T)
    bf16_t* W2t  = W1t + (size_t)Hc * DIN;         // Hc*Hc   (= W2^T)
    bf16_t* Wl1t = W2t + (size_t)Hc * Hc;          // HMc*Hc  (= Wl1^T)

    const int* srcv = ei;
    const int* dstv = ei + Ne;

    // ---- one-time per launch: dinv + CSR + bf16 weights/x ----
    deg_init_k<<<(Nn + 255) / 256, 256, 0, stream>>>(dinv, cnt);
    deg_edge_k<<<(Ne + 255) / 256, 256, 0, stream>>>(ew, dstv, dinv, cnt);
    dinv_k<<<(Nn + 255) / 256, 256, 0, stream>>>(dinv);
    scanA_k<<<NB_SCAN, 256, 0, stream>>>(cnt, row_ptr, blk);
    scanB_k<<<1, 128, 0, stream>>>(blk);
    scanC_k<<<NB_SCAN, 256, 0, stream>>>(row_ptr, blk, cursor);
    csr_fill_k<<<(Ne + 255) / 256, 256, 0, stream>>>(srcv, dstv, ew, dinv, cursor,
                                                     csr_src, csr_coef);
    transpose_bf16_k<DIN, Hc><<<dim3(Hc / 32, DIN / 32), 256, 0, stream>>>(W1, W1t);
    transpose_bf16_k<Hc, Hc><<<dim3(Hc / 32, Hc / 32), 256, 0, stream>>>(W2, W2t);
    transpose_bf16_k<Hc, HMc><<<dim3(HMc / 32, Hc / 32), 256, 0, stream>>>(Wl1, Wl1t);
    cvt_bf16_k<<<(Nn * DIN / 4 + 255) / 256, 256, 0, stream>>>(
        (const float4*)x, (bf16x4*)xb, Nn * DIN / 4);

    const int MB = (Nn + 127) / 128;               // 157 row-blocks

    // layer 1:  (A X) W1  — aggregate first (128-dim), then GEMM with fused BN stats
    spmm_x_k<<<4 * ((Nn + 63) / 64), 256, 0, stream>>>(
        (const bf16x8*)xb, row_ptr, csr_src, csr_coef, dinv, (bf16x8*)xagg);
    zero_stats_k<<<8, 256, 0, stream>>>(s1);
    gemm_bf16_k<Hc, DIN, false, false, true, true><<<dim3(Hc / 128, MB), 256, 0, stream>>>(
        xagg, W1t, nullptr, hgem, Nn, s1, s2);
    bn_apply_k<<<Nn * Hc / 8 / 256, 256, 0, stream>>>(
        (const bf16x8*)hgem, s1, s2, gam1, bet1, (bf16x8*)hbf);

    // layer 2:  GEMM, aggregate (1024-dim, panel-partitioned), BN
    gemm_bf16_k<Hc, Hc, false, false, true, false><<<dim3(Hc / 128, MB), 256, 0, stream>>>(
        hbf, W2t, nullptr, hgem, Nn, nullptr, nullptr);
    spmm_h_k<<<8 * (Nn / 16), 256, 0, stream>>>(
        (const bf16x8*)hgem, row_ptr, csr_src, csr_coef, dinv, (bf16x8*)hbf);
    zero_stats_k<<<8, 256, 0, stream>>>(s1);
    bn_stats_k<<<dim3(Hc / 256, 80), 256, 0, stream>>>(hbf, s1, s2);
    bn_apply_k<<<Nn * Hc / 8 / 256, 256, 0, stream>>>(
        (const bf16x8*)hbf, s1, s2, gam2, bet2, (bf16x8*)hgem);

    // MLP head: z = relu(h @ Wl1 + bl1) (fp32 out), then fused GEMM+log_softmax
    gemm_bf16_k<HMc, Hc, true, true, false, false><<<dim3(HMc / 128, MB), 256, 0, stream>>>(
        hgem, Wl1t, bl1, zhead, Nn, nullptr, nullptr);
    head_k<<<Nn / 4, 256, 0, stream>>>(zhead, Wl2, bl2, out);
}